// Round 2
// baseline (1025.415 us; speedup 1.0000x reference)
//
#include <hip/hip_runtime.h>
#include <hip/hip_bf16.h>

typedef __hip_bfloat16 bf16;
typedef __attribute__((ext_vector_type(8))) short s8v;   // 8 bf16 = 4 VGPRs
typedef __attribute__((ext_vector_type(4))) float f4v;

#define NPIX 4096
#define CDIM 256

// ---- 8-element loaders -> bf16x8 (s8v) --------------------------------------
__device__ inline s8v ld8(const bf16* p) { return *(const s8v*)p; }
__device__ inline s8v ld8(const float* p) {
  float4 f0 = *(const float4*)p;
  float4 f1 = *(const float4*)(p + 4);
  s8v r; bf16* e = (bf16*)&r;
  e[0] = __float2bfloat16(f0.x); e[1] = __float2bfloat16(f0.y);
  e[2] = __float2bfloat16(f0.z); e[3] = __float2bfloat16(f0.w);
  e[4] = __float2bfloat16(f1.x); e[5] = __float2bfloat16(f1.y);
  e[6] = __float2bfloat16(f1.z); e[7] = __float2bfloat16(f1.w);
  return r;
}

// ---------------------------------------------------------------------------
// Generic MFMA GEMM: C[M x N] = A*B (+ bias[row]), fp32 accum, bf16 out.
// TA=0: A stored [M x K].  TA=1: A stored [K x M] (computes A^T * B).
// TB=0: B stored [K x N].  TB=1: B stored [N x K] (computes A * B^T).
// A/B element types templated (float sources converted to bf16 at staging).
// Tile 64x64, BK=32; 256 threads = 4 waves; wave w owns rows [w*16, w*16+16).
// ---------------------------------------------------------------------------
template<int TA, int TB, int BIAS, typename TAe, typename TBe>
__global__ __launch_bounds__(256) void gemm_k(
    const TAe* __restrict__ A, const TBe* __restrict__ Bm,
    const float* __restrict__ bias, bf16* __restrict__ Cm,
    int M, int N, int K, long abat, long bbat, long cbat)
{
  __shared__ bf16 a_s[64][40];   // [m][k], padded
  __shared__ bf16 b_s[64][40];   // [n][k]
  const int tid = threadIdx.x;
  A  += blockIdx.z * abat;
  Bm += blockIdx.z * bbat;
  Cm += blockIdx.z * cbat;
  const int m0 = blockIdx.y * 64, n0 = blockIdx.x * 64;
  const int w = tid >> 6, lane = tid & 63;
  const int l15 = lane & 15, oct = lane >> 4;
  const int nchunk = K >> 5;

  f4v acc[4];
  #pragma unroll
  for (int i = 0; i < 4; ++i) acc[i] = (f4v){0.f, 0.f, 0.f, 0.f};

  int a_i0, a_i1, b_i0, b_i1;
  if (TA == 0) { a_i0 = tid >> 2; a_i1 = (tid & 3) * 8; }  // (m, k-off)
  else         { a_i0 = tid >> 3; a_i1 = (tid & 7) * 8; }  // (k, m-off)
  if (TB == 0) { b_i0 = tid >> 3; b_i1 = (tid & 7) * 8; }  // (k, n-off)
  else         { b_i0 = tid >> 2; b_i1 = (tid & 3) * 8; }  // (n, k-off)

  s8v pa, pb;
  auto ldA = [&](int kc, s8v& d) {
    if (TA == 0) {
      if (m0 + a_i0 < M) d = ld8(A + (long)(m0 + a_i0) * K + kc * 32 + a_i1);
      else d = (s8v){0,0,0,0,0,0,0,0};
    } else {
      d = ld8(A + (long)(kc * 32 + a_i0) * M + m0 + a_i1);
    }
  };
  auto ldB = [&](int kc, s8v& d) {
    if (TB == 0) d = ld8(Bm + (long)(kc * 32 + b_i0) * N + n0 + b_i1);
    else         d = ld8(Bm + (long)(n0 + b_i0) * K + kc * 32 + b_i1);
  };

  ldA(0, pa); ldB(0, pb);
  for (int kc = 0; kc < nchunk; ++kc) {
    if (TA == 0) {
      *(s8v*)&a_s[a_i0][a_i1] = pa;
    } else {
      const bf16* e = (const bf16*)&pa;
      #pragma unroll
      for (int j = 0; j < 8; ++j) a_s[a_i1 + j][a_i0] = e[j];
    }
    if (TB == 0) {
      const bf16* e = (const bf16*)&pb;
      #pragma unroll
      for (int j = 0; j < 8; ++j) b_s[b_i1 + j][b_i0] = e[j];
    } else {
      *(s8v*)&b_s[b_i0][b_i1] = pb;
    }
    __syncthreads();
    if (kc + 1 < nchunk) { ldA(kc + 1, pa); ldB(kc + 1, pb); }
    // A-frag: A[m=l15][k=oct*8+j]; B-frag: B[k=oct*8+j][n=l15]
    s8v af = *(const s8v*)&a_s[w * 16 + l15][oct * 8];
    #pragma unroll
    for (int nt = 0; nt < 4; ++nt) {
      s8v bfr = *(const s8v*)&b_s[nt * 16 + l15][oct * 8];
      acc[nt] = __builtin_amdgcn_mfma_f32_16x16x32_bf16(af, bfr, acc[nt], 0, 0, 0);
    }
    __syncthreads();
  }
  // D layout: row = oct*4 + reg, col = l15
  const int gm_base = m0 + w * 16 + oct * 4;
  #pragma unroll
  for (int nt = 0; nt < 4; ++nt) {
    #pragma unroll
    for (int r = 0; r < 4; ++r) {
      int gm = gm_base + r;
      if (gm < M) {
        float vv = acc[nt][r];
        if (BIAS) vv += bias[gm];
        Cm[(long)gm * N + n0 + nt * 16 + l15] = __float2bfloat16(vv);
      }
    }
  }
}

// ---- row softmax over 4096, in place, bf16 storage / fp32 math -------------
__global__ __launch_bounds__(256) void softmax_k(bf16* __restrict__ S)
{
  __shared__ float red[8];
  const int tid = threadIdx.x;
  bf16* p = S + (long)blockIdx.x * NPIX + tid * 16;
  s8v r0 = *(const s8v*)p;
  s8v r1 = *(const s8v*)(p + 8);
  const bf16* e0 = (const bf16*)&r0;
  const bf16* e1 = (const bf16*)&r1;
  float v[16];
  #pragma unroll
  for (int j = 0; j < 8; ++j) { v[j] = __bfloat162float(e0[j]); v[8 + j] = __bfloat162float(e1[j]); }
  float m = -3.0e38f;
  #pragma unroll
  for (int j = 0; j < 16; ++j) m = fmaxf(m, v[j]);
  #pragma unroll
  for (int s = 32; s; s >>= 1) m = fmaxf(m, __shfl_xor(m, s));
  if ((tid & 63) == 0) red[tid >> 6] = m;
  __syncthreads();
  m = fmaxf(fmaxf(red[0], red[1]), fmaxf(red[2], red[3]));
  float sum = 0.f;
  #pragma unroll
  for (int j = 0; j < 16; ++j) { v[j] = __expf(v[j] - m); sum += v[j]; }
  #pragma unroll
  for (int s = 32; s; s >>= 1) sum += __shfl_xor(sum, s);
  if ((tid & 63) == 0) red[4 + (tid >> 6)] = sum;
  __syncthreads();
  sum = red[4] + red[5] + red[6] + red[7];
  float inv = 1.f / sum;
  s8v o0, o1v;
  bf16* f0 = (bf16*)&o0; bf16* f1 = (bf16*)&o1v;
  #pragma unroll
  for (int j = 0; j < 8; ++j) {
    f0[j] = __float2bfloat16(v[j] * inv);
    f1[j] = __float2bfloat16(v[8 + j] * inv);
  }
  *(s8v*)p = o0; *(s8v*)(p + 8) = o1v;
}

// ---- im2col for 3x3 SAME conv (bf16 src -> bf16 col[c*9+j][n]) -------------
__global__ __launch_bounds__(256) void im2col_k(const bf16* __restrict__ x,
                                                bf16* __restrict__ col)
{
  int idx = blockIdx.x * 256 + threadIdx.x;         // 2304*4096 total
  int n = idx & 4095, kk = idx >> 12;
  int c = kk / 9, j = kk - c * 9;
  int h = (n >> 6) + j / 3 - 1;
  int ww = (n & 63) + j % 3 - 1;
  bf16 val = __float2bfloat16(0.f);
  if ((unsigned)h < 64u && (unsigned)ww < 64u) val = x[c * 4096 + h * 64 + ww];
  col[idx] = val;
}

// ---- 16-element row load/store helpers --------------------------------------
__device__ inline void ld16(const bf16* p, float* v) {
  s8v r0 = *(const s8v*)p, r1 = *(const s8v*)(p + 8);
  const bf16* e0 = (const bf16*)&r0; const bf16* e1 = (const bf16*)&r1;
  #pragma unroll
  for (int j = 0; j < 8; ++j) { v[j] = __bfloat162float(e0[j]); v[8 + j] = __bfloat162float(e1[j]); }
}
__device__ inline void ld16(const float* p, float* v) {
  #pragma unroll
  for (int q = 0; q < 4; ++q) {
    float4 f = *(const float4*)(p + q * 4);
    v[q * 4 + 0] = f.x; v[q * 4 + 1] = f.y; v[q * 4 + 2] = f.z; v[q * 4 + 3] = f.w;
  }
}
__device__ inline void st16(bf16* p, const float* v) {
  s8v o0, o1v; bf16* f0 = (bf16*)&o0; bf16* f1 = (bf16*)&o1v;
  #pragma unroll
  for (int j = 0; j < 8; ++j) { f0[j] = __float2bfloat16(v[j]); f1[j] = __float2bfloat16(v[8 + j]); }
  *(s8v*)p = o0; *(s8v*)(p + 8) = o1v;
}
__device__ inline void st16(float* p, const float* v) {
  #pragma unroll
  for (int q = 0; q < 4; ++q) {
    float4 f; f.x = v[q * 4 + 0]; f.y = v[q * 4 + 1]; f.z = v[q * 4 + 2]; f.w = v[q * 4 + 3];
    *(float4*)(p + q * 4) = f;
  }
}

// ---- fused InstanceNorm: out = inorm(g*a + b) per row of 4096 --------------
template<typename TAe, typename TBe, typename TOe, int G>
__global__ __launch_bounds__(256) void inorm_k(
    const TAe* __restrict__ a, const TBe* __restrict__ b,
    const float* __restrict__ g, TOe* __restrict__ out)
{
  __shared__ float red[8];
  const int tid = threadIdx.x;
  const long base = (long)blockIdx.x * NPIX + tid * 16;
  float gv = G ? *g : 1.f;
  float va[16], vbv[16], v[16];
  ld16(a + base, va);
  ld16(b + base, vbv);
  #pragma unroll
  for (int j = 0; j < 16; ++j) v[j] = gv * va[j] + vbv[j];
  float sum = 0.f, sq = 0.f;
  #pragma unroll
  for (int j = 0; j < 16; ++j) { sum += v[j]; sq += v[j] * v[j]; }
  #pragma unroll
  for (int s = 32; s; s >>= 1) { sum += __shfl_xor(sum, s); sq += __shfl_xor(sq, s); }
  if ((tid & 63) == 0) { red[tid >> 6] = sum; red[4 + (tid >> 6)] = sq; }
  __syncthreads();
  sum = red[0] + red[1] + red[2] + red[3];
  sq  = red[4] + red[5] + red[6] + red[7];
  float mean = sum * (1.f / NPIX);
  float var  = fmaxf(sq * (1.f / NPIX) - mean * mean, 0.f);
  float rstd = rsqrtf(var + 1e-5f);
  float o[16];
  #pragma unroll
  for (int j = 0; j < 16; ++j) o[j] = (v[j] - mean) * rstd;
  st16(out + base, o);
}

// ---- host-side helpers ------------------------------------------------------
static const long CN  = (long)CDIM * NPIX;   // per-batch elems, C=256
static const long C8N = (long)32 * NPIX;     // per-batch elems, C/8=32

template<typename TQK, typename TV>
static void run_attn(const TQK* qksrc, const TV* vsrc,
                     const float* wq, const float* bq,
                     const float* wk, const float* bk,
                     const float* wv, const float* bv,
                     bf16* qb, bf16* kb, bf16* vb, bf16* t0, bf16* Sb,
                     hipStream_t stream)
{
  dim3 TB(256);
  gemm_k<0,0,1,float,TQK><<<dim3(64,1,2), TB, 0, stream>>>(wq, qksrc, bq, qb, 32,  NPIX, 256, 0L, CN, C8N);
  gemm_k<0,0,1,float,TQK><<<dim3(64,1,2), TB, 0, stream>>>(wk, qksrc, bk, kb, 32,  NPIX, 256, 0L, CN, C8N);
  gemm_k<0,0,1,float,TV ><<<dim3(64,4,2), TB, 0, stream>>>(wv, vsrc,  bv, vb, 256, NPIX, 256, 0L, CN, CN);
  for (int b = 0; b < 2; ++b) {
    // S[n][m] = sum_d q[d][n] k[d][m]  (A^T * B, K=32)
    gemm_k<1,0,0,bf16,bf16><<<dim3(64,64,1), TB, 0, stream>>>(qb + b * C8N, kb + b * C8N,
                                                              nullptr, Sb, NPIX, NPIX, 32, 0L, 0L, 0L);
    softmax_k<<<dim3(NPIX), TB, 0, stream>>>(Sb);
    // O[c][n] = sum_m v[c][m] P[n][m]  (A * B^T, K=4096)
    gemm_k<0,1,0,bf16,bf16><<<dim3(64,4,1), TB, 0, stream>>>(vb + b * CN, Sb, nullptr,
                                                             t0 + b * CN, 256, NPIX, NPIX, 0L, 0L, 0L);
  }
}

static void run_conv(const bf16* src, const float* cw, const float* cb,
                     bf16* col, bf16* dst, hipStream_t stream)
{
  dim3 TB(256);
  for (int b = 0; b < 2; ++b) {
    im2col_k<<<dim3(36864), TB, 0, stream>>>(src + b * CN, col);
    gemm_k<0,0,1,float,bf16><<<dim3(64,4,1), TB, 0, stream>>>(cw, col, cb, dst + b * CN,
                                                              256, NPIX, 2304, 0L, 0L, 0L);
  }
}

// ---------------------------------------------------------------------------
extern "C" void kernel_launch(void* const* d_in, const int* in_sizes, int n_in,
                              void* d_out, int out_size, void* d_ws, size_t ws_size,
                              hipStream_t stream)
{
  (void)in_sizes; (void)n_in; (void)out_size; (void)ws_size;
  const float* x = (const float*)d_in[0];
  const float* y = (const float*)d_in[1];
  auto W = [&](int i) { return (const float*)d_in[i]; };

  char* wp = (char*)d_ws;
  auto take = [&](size_t nbytes) { char* p = wp; wp += (nbytes + 255) & ~(size_t)255; return p; };
  bf16* qb  = (bf16*)take(2 * C8N * 2);
  bf16* kb  = (bf16*)take(2 * C8N * 2);
  bf16* vb  = (bf16*)take(2 * CN * 2);               // also conv output
  bf16* t0  = (bf16*)take(2 * CN * 2);               // attention O
  bf16* u1  = (bf16*)take(2 * CN * 2);               // out_1 / top o1
  bf16* u2  = (bf16*)take(2 * CN * 2);               // out_2
  bf16* u3  = (bf16*)take(2 * CN * 2);               // out_3
  bf16* u4  = (bf16*)take(2 * CN * 2);               // top o2
  bf16* Sb  = (bf16*)take((size_t)NPIX * NPIX * 2);  // scores, one batch
  bf16* col = (bf16*)take((size_t)2304 * NPIX * 2);  // im2col, one batch

  dim3 TB(256);

  // stage A: out_1 = inorm(sa1(x)); out_2 = inorm(out_1 + conv1(out_1))
  run_attn<float,float>(x, x, W(2), W(3), W(4), W(5), W(6), W(7), qb, kb, vb, t0, Sb, stream);
  inorm_k<bf16,float,bf16,1><<<dim3(512), TB, 0, stream>>>(t0, x, W(8), u1);
  run_conv(u1, W(23), W(24), col, vb, stream);
  inorm_k<bf16,bf16,bf16,0><<<dim3(512), TB, 0, stream>>>(u1, vb, nullptr, u2);

  // stage B: out_3 = inorm(sa2(y))
  run_attn<float,float>(y, y, W(9), W(10), W(11), W(12), W(13), W(14), qb, kb, vb, t0, Sb, stream);
  inorm_k<bf16,float,bf16,1><<<dim3(512), TB, 0, stream>>>(t0, y, W(15), u3);

  // stage C: top attention (q,k from out_2; v from out_3), residual = y
  run_attn<bf16,bf16>(u2, u3, W(16), W(17), W(18), W(19), W(20), W(21), qb, kb, vb, t0, Sb, stream);
  inorm_k<bf16,float,bf16,1><<<dim3(512), TB, 0, stream>>>(t0, y, W(22), u1);   // o1
  inorm_k<bf16,bf16,bf16,0><<<dim3(512), TB, 0, stream>>>(u1, u3, nullptr, u4); // o2
  run_conv(u4, W(25), W(26), col, vb, stream);
  inorm_k<bf16,bf16,float,0><<<dim3(512), TB, 0, stream>>>(u4, vb, nullptr, (float*)d_out);
}

// Round 3
// 781.422 us; speedup vs baseline: 1.3122x; 1.3122x over previous
//
#include <hip/hip_runtime.h>
#include <hip/hip_bf16.h>

typedef __hip_bfloat16 bf16;
typedef __attribute__((ext_vector_type(8))) short s8v;   // 8 bf16 = 4 VGPRs
typedef __attribute__((ext_vector_type(4))) short s4v;   // 4 bf16
typedef __attribute__((ext_vector_type(4))) float f4v;

#define NPIX 4096
#define CDIM 256

// ---- 8-element loaders -> bf16x8 (s8v) --------------------------------------
__device__ inline s8v ld8(const bf16* p) { return *(const s8v*)p; }
__device__ inline s8v ld8(const float* p) {
  float4 f0 = *(const float4*)p;
  float4 f1 = *(const float4*)(p + 4);
  s8v r; bf16* e = (bf16*)&r;
  e[0] = __float2bfloat16(f0.x); e[1] = __float2bfloat16(f0.y);
  e[2] = __float2bfloat16(f0.z); e[3] = __float2bfloat16(f0.w);
  e[4] = __float2bfloat16(f1.x); e[5] = __float2bfloat16(f1.y);
  e[6] = __float2bfloat16(f1.z); e[7] = __float2bfloat16(f1.w);
  return r;
}
__device__ inline void cstore(bf16* p, float v)  { *p = __float2bfloat16(v); }
__device__ inline void cstore(float* p, float v) { *p = v; }

// ---------------------------------------------------------------------------
// Generic MFMA GEMM: C[M x N] = A*B (+ bias[row]), fp32 accum.
// TA=0: A stored [M x K].  TA=1: A stored [K x M] (computes A^T * B).
// TB=0: B stored [K x N].  TB=1: B stored [N x K] (computes A * B^T).
// SPLIT=0: blockIdx.z = batch (abat/bbat/cbat strides), nchunk = K/32.
// SPLIT=1: blockIdx.z = K-slice; block covers chunks [z*nchunk, (z+1)*nchunk);
//          output fp32 partials at Cm + z*cbat (cbat = M*N), abat=bbat=0.
// Tile 64x64, BK=32; 256 threads = 4 waves; wave w owns rows [w*16, w*16+16).
// ---------------------------------------------------------------------------
template<int TA, int TB, int BIAS, int SPLIT, typename TAe, typename TBe, typename TOe>
__global__ __launch_bounds__(256) void gemm_k(
    const TAe* __restrict__ A, const TBe* __restrict__ Bm,
    const float* __restrict__ bias, TOe* __restrict__ Cm,
    int M, int N, int K, long abat, long bbat, long cbat, int nchunk)
{
  __shared__ bf16 a_s[64][40];   // [m][k], padded (+8) to break bank strides
  __shared__ bf16 b_s[64][40];   // [n][k]
  const int tid = threadIdx.x;
  A  += blockIdx.z * abat;
  Bm += blockIdx.z * bbat;
  Cm += blockIdx.z * cbat;
  const int m0 = blockIdx.y * 64, n0 = blockIdx.x * 64;
  const int w = tid >> 6, lane = tid & 63;
  const int l15 = lane & 15, oct = lane >> 4;
  const int kc0 = SPLIT ? blockIdx.z * nchunk : 0;
  const int kc1 = kc0 + nchunk;

  f4v acc[4];
  #pragma unroll
  for (int i = 0; i < 4; ++i) acc[i] = (f4v){0.f, 0.f, 0.f, 0.f};

  int a_i0, a_i1, b_i0, b_i1;
  if (TA == 0) { a_i0 = tid >> 2; a_i1 = (tid & 3) * 8; }  // (m, k-off)
  else         { a_i0 = tid >> 3; a_i1 = (tid & 7) * 8; }  // (k, m-off)
  if (TB == 0) { b_i0 = tid >> 3; b_i1 = (tid & 7) * 8; }  // (k, n-off)
  else         { b_i0 = tid >> 2; b_i1 = (tid & 3) * 8; }  // (n, k-off)

  s8v pa, pb;
  auto ldA = [&](int kc, s8v& d) {
    if (TA == 0) {
      if (m0 + a_i0 < M) d = ld8(A + (long)(m0 + a_i0) * K + kc * 32 + a_i1);
      else d = (s8v){0,0,0,0,0,0,0,0};
    } else {
      d = ld8(A + (long)(kc * 32 + a_i0) * M + m0 + a_i1);
    }
  };
  auto ldB = [&](int kc, s8v& d) {
    if (TB == 0) d = ld8(Bm + (long)(kc * 32 + b_i0) * N + n0 + b_i1);
    else         d = ld8(Bm + (long)(n0 + b_i0) * K + kc * 32 + b_i1);
  };

  ldA(kc0, pa); ldB(kc0, pb);
  for (int kc = kc0; kc < kc1; ++kc) {
    if (TA == 0) {
      *(s8v*)&a_s[a_i0][a_i1] = pa;
    } else {
      const bf16* e = (const bf16*)&pa;
      #pragma unroll
      for (int j = 0; j < 8; ++j) a_s[a_i1 + j][a_i0] = e[j];
    }
    if (TB == 0) {
      const bf16* e = (const bf16*)&pb;
      #pragma unroll
      for (int j = 0; j < 8; ++j) b_s[b_i1 + j][b_i0] = e[j];
    } else {
      *(s8v*)&b_s[b_i0][b_i1] = pb;
    }
    __syncthreads();
    if (kc + 1 < kc1) { ldA(kc + 1, pa); ldB(kc + 1, pb); }
    // A-frag: A[m=l15][k=oct*8+j]; B-frag: B[k=oct*8+j][n=l15]
    s8v af = *(const s8v*)&a_s[w * 16 + l15][oct * 8];
    #pragma unroll
    for (int nt = 0; nt < 4; ++nt) {
      s8v bfr = *(const s8v*)&b_s[nt * 16 + l15][oct * 8];
      acc[nt] = __builtin_amdgcn_mfma_f32_16x16x32_bf16(af, bfr, acc[nt], 0, 0, 0);
    }
    __syncthreads();
  }
  // D layout: row = oct*4 + reg, col = l15
  const int gm_base = m0 + w * 16 + oct * 4;
  #pragma unroll
  for (int nt = 0; nt < 4; ++nt) {
    #pragma unroll
    for (int r = 0; r < 4; ++r) {
      int gm = gm_base + r;
      if (gm < M) {
        float vv = acc[nt][r];
        if (BIAS) vv += bias[gm];
        cstore(Cm + (long)gm * N + n0 + nt * 16 + l15, vv);
      }
    }
  }
}

// ---- split-K reducer: out = bf16(sum_s part[s] + bias) ----------------------
template<int BIAS>
__global__ __launch_bounds__(256) void reduce_k(
    const float* __restrict__ part, const float* __restrict__ bias,
    bf16* __restrict__ out, int MN, int N, int nsplit)
{
  const int i4 = (blockIdx.x * 256 + threadIdx.x) * 4;
  float4 s = *(const float4*)(part + i4);
  for (int p = 1; p < nsplit; ++p) {
    float4 t = *(const float4*)(part + (long)p * MN + i4);
    s.x += t.x; s.y += t.y; s.z += t.z; s.w += t.w;
  }
  if (BIAS) { float b = bias[i4 / N]; s.x += b; s.y += b; s.z += b; s.w += b; }
  s4v o; bf16* e = (bf16*)&o;
  e[0] = __float2bfloat16(s.x); e[1] = __float2bfloat16(s.y);
  e[2] = __float2bfloat16(s.z); e[3] = __float2bfloat16(s.w);
  *(s4v*)(out + i4) = o;
}

// ---- row softmax over 4096, in place, bf16 storage / fp32 math -------------
__global__ __launch_bounds__(256) void softmax_k(bf16* __restrict__ S)
{
  __shared__ float red[8];
  const int tid = threadIdx.x;
  bf16* p = S + (long)blockIdx.x * NPIX + tid * 16;
  s8v r0 = *(const s8v*)p;
  s8v r1 = *(const s8v*)(p + 8);
  const bf16* e0 = (const bf16*)&r0;
  const bf16* e1 = (const bf16*)&r1;
  float v[16];
  #pragma unroll
  for (int j = 0; j < 8; ++j) { v[j] = __bfloat162float(e0[j]); v[8 + j] = __bfloat162float(e1[j]); }
  float m = -3.0e38f;
  #pragma unroll
  for (int j = 0; j < 16; ++j) m = fmaxf(m, v[j]);
  #pragma unroll
  for (int s = 32; s; s >>= 1) m = fmaxf(m, __shfl_xor(m, s));
  if ((tid & 63) == 0) red[tid >> 6] = m;
  __syncthreads();
  m = fmaxf(fmaxf(red[0], red[1]), fmaxf(red[2], red[3]));
  float sum = 0.f;
  #pragma unroll
  for (int j = 0; j < 16; ++j) { v[j] = __expf(v[j] - m); sum += v[j]; }
  #pragma unroll
  for (int s = 32; s; s >>= 1) sum += __shfl_xor(sum, s);
  if ((tid & 63) == 0) red[4 + (tid >> 6)] = sum;
  __syncthreads();
  sum = red[4] + red[5] + red[6] + red[7];
  float inv = 1.f / sum;
  s8v o0, o1v;
  bf16* f0 = (bf16*)&o0; bf16* f1 = (bf16*)&o1v;
  #pragma unroll
  for (int j = 0; j < 8; ++j) {
    f0[j] = __float2bfloat16(v[j] * inv);
    f1[j] = __float2bfloat16(v[8 + j] * inv);
  }
  *(s8v*)p = o0; *(s8v*)(p + 8) = o1v;
}

// ---- im2col for 3x3 SAME conv (bf16 src -> bf16 col[c*9+j][n]) -------------
__global__ __launch_bounds__(256) void im2col_k(const bf16* __restrict__ x,
                                                bf16* __restrict__ col)
{
  int idx = blockIdx.x * 256 + threadIdx.x;         // 2304*4096 total
  int n = idx & 4095, kk = idx >> 12;
  int c = kk / 9, j = kk - c * 9;
  int h = (n >> 6) + j / 3 - 1;
  int ww = (n & 63) + j % 3 - 1;
  bf16 val = __float2bfloat16(0.f);
  if ((unsigned)h < 64u && (unsigned)ww < 64u) val = x[c * 4096 + h * 64 + ww];
  col[idx] = val;
}

// ---- 16-element row load/store helpers --------------------------------------
__device__ inline void ld16(const bf16* p, float* v) {
  s8v r0 = *(const s8v*)p, r1 = *(const s8v*)(p + 8);
  const bf16* e0 = (const bf16*)&r0; const bf16* e1 = (const bf16*)&r1;
  #pragma unroll
  for (int j = 0; j < 8; ++j) { v[j] = __bfloat162float(e0[j]); v[8 + j] = __bfloat162float(e1[j]); }
}
__device__ inline void ld16(const float* p, float* v) {
  #pragma unroll
  for (int q = 0; q < 4; ++q) {
    float4 f = *(const float4*)(p + q * 4);
    v[q * 4 + 0] = f.x; v[q * 4 + 1] = f.y; v[q * 4 + 2] = f.z; v[q * 4 + 3] = f.w;
  }
}
__device__ inline void st16(bf16* p, const float* v) {
  s8v o0, o1v; bf16* f0 = (bf16*)&o0; bf16* f1 = (bf16*)&o1v;
  #pragma unroll
  for (int j = 0; j < 8; ++j) { f0[j] = __float2bfloat16(v[j]); f1[j] = __float2bfloat16(v[8 + j]); }
  *(s8v*)p = o0; *(s8v*)(p + 8) = o1v;
}
__device__ inline void st16(float* p, const float* v) {
  #pragma unroll
  for (int q = 0; q < 4; ++q) {
    float4 f; f.x = v[q * 4 + 0]; f.y = v[q * 4 + 1]; f.z = v[q * 4 + 2]; f.w = v[q * 4 + 3];
    *(float4*)(p + q * 4) = f;
  }
}

// ---- fused InstanceNorm: out = inorm(g*a + b) per row of 4096 --------------
template<typename TAe, typename TBe, typename TOe, int G>
__global__ __launch_bounds__(256) void inorm_k(
    const TAe* __restrict__ a, const TBe* __restrict__ b,
    const float* __restrict__ g, TOe* __restrict__ out)
{
  __shared__ float red[8];
  const int tid = threadIdx.x;
  const long base = (long)blockIdx.x * NPIX + tid * 16;
  float gv = G ? *g : 1.f;
  float va[16], vbv[16], v[16];
  ld16(a + base, va);
  ld16(b + base, vbv);
  #pragma unroll
  for (int j = 0; j < 16; ++j) v[j] = gv * va[j] + vbv[j];
  float sum = 0.f, sq = 0.f;
  #pragma unroll
  for (int j = 0; j < 16; ++j) { sum += v[j]; sq += v[j] * v[j]; }
  #pragma unroll
  for (int s = 32; s; s >>= 1) { sum += __shfl_xor(sum, s); sq += __shfl_xor(sq, s); }
  if ((tid & 63) == 0) { red[tid >> 6] = sum; red[4 + (tid >> 6)] = sq; }
  __syncthreads();
  sum = red[0] + red[1] + red[2] + red[3];
  sq  = red[4] + red[5] + red[6] + red[7];
  float mean = sum * (1.f / NPIX);
  float var  = fmaxf(sq * (1.f / NPIX) - mean * mean, 0.f);
  float rstd = rsqrtf(var + 1e-5f);
  float o[16];
  #pragma unroll
  for (int j = 0; j < 16; ++j) o[j] = (v[j] - mean) * rstd;
  st16(out + base, o);
}

// ---- host-side helpers ------------------------------------------------------
static const long CN  = (long)CDIM * NPIX;   // per-batch elems, C=256
static const long C8N = (long)32 * NPIX;     // per-batch elems, C/8=32
static const long MN  = (long)CDIM * NPIX;   // skinny-GEMM output elems

template<typename TQK, typename TV>
static void run_attn(const TQK* qksrc, const TV* vsrc,
                     const float* wq, const float* bq,
                     const float* wk, const float* bk,
                     const float* wv, const float* bv,
                     bf16* qb, bf16* kb, bf16* vb, bf16* t0, bf16* Sb, float* part,
                     hipStream_t stream)
{
  dim3 TB(256);
  gemm_k<0,0,1,0,float,TQK,bf16><<<dim3(64,1,2), TB, 0, stream>>>(wq, qksrc, bq, qb, 32,  NPIX, 256, 0L, CN, C8N, 8);
  gemm_k<0,0,1,0,float,TQK,bf16><<<dim3(64,1,2), TB, 0, stream>>>(wk, qksrc, bk, kb, 32,  NPIX, 256, 0L, CN, C8N, 8);
  gemm_k<0,0,1,0,float,TV ,bf16><<<dim3(64,4,2), TB, 0, stream>>>(wv, vsrc,  bv, vb, 256, NPIX, 256, 0L, CN, CN, 8);
  for (int b = 0; b < 2; ++b) {
    // S[n][m] = sum_d q[d][n] k[d][m]  (A^T * B, K=32)
    gemm_k<1,0,0,0,bf16,bf16,bf16><<<dim3(64,64,1), TB, 0, stream>>>(qb + b * C8N, kb + b * C8N,
                                                                     nullptr, Sb, NPIX, NPIX, 32, 0L, 0L, 0L, 1);
    softmax_k<<<dim3(NPIX), TB, 0, stream>>>(Sb);
    // O[c][n] = sum_m v[c][m] P[n][m]  (A * B^T, K=4096), split-K=8
    gemm_k<0,1,0,1,bf16,bf16,float><<<dim3(64,4,8), TB, 0, stream>>>(vb + b * CN, Sb, nullptr,
                                                                     part, 256, NPIX, NPIX, 0L, 0L, MN, 16);
    reduce_k<0><<<dim3(1024), TB, 0, stream>>>(part, nullptr, t0 + b * CN, (int)MN, NPIX, 8);
  }
}

static void run_conv(const bf16* src, const float* cw, const float* cb,
                     bf16* col, float* part, bf16* dst, hipStream_t stream)
{
  dim3 TB(256);
  for (int b = 0; b < 2; ++b) {
    im2col_k<<<dim3(36864), TB, 0, stream>>>(src + b * CN, col);
    // K = 2304 = 72 chunks, split-K=8 -> 9 chunks per slice
    gemm_k<0,0,0,1,float,bf16,float><<<dim3(64,4,8), TB, 0, stream>>>(cw, col, nullptr, part,
                                                                      256, NPIX, 2304, 0L, 0L, MN, 9);
    reduce_k<1><<<dim3(1024), TB, 0, stream>>>(part, cb, dst + b * CN, (int)MN, NPIX, 8);
  }
}

// ---------------------------------------------------------------------------
extern "C" void kernel_launch(void* const* d_in, const int* in_sizes, int n_in,
                              void* d_out, int out_size, void* d_ws, size_t ws_size,
                              hipStream_t stream)
{
  (void)in_sizes; (void)n_in; (void)out_size; (void)ws_size;
  const float* x = (const float*)d_in[0];
  const float* y = (const float*)d_in[1];
  auto W = [&](int i) { return (const float*)d_in[i]; };

  char* wp = (char*)d_ws;
  auto take = [&](size_t nbytes) { char* p = wp; wp += (nbytes + 255) & ~(size_t)255; return p; };
  bf16* qb   = (bf16*)take(2 * C8N * 2);
  bf16* kb   = (bf16*)take(2 * C8N * 2);
  bf16* vb   = (bf16*)take(2 * CN * 2);               // also conv output
  bf16* t0   = (bf16*)take(2 * CN * 2);               // attention O
  bf16* u1   = (bf16*)take(2 * CN * 2);               // out_1 / top o1
  bf16* u2   = (bf16*)take(2 * CN * 2);               // out_2
  bf16* u3   = (bf16*)take(2 * CN * 2);               // out_3
  bf16* u4   = (bf16*)take(2 * CN * 2);               // top o2
  bf16* Sb   = (bf16*)take((size_t)NPIX * NPIX * 2);  // scores (attn) / im2col (conv)
  bf16* col  = Sb;                                    // aliased: never live together
  float* part = (float*)take((size_t)8 * MN * 4);     // split-K fp32 partials, 32 MB

  dim3 TB(256);

  // stage A: out_1 = inorm(sa1(x)); out_2 = inorm(out_1 + conv1(out_1))
  run_attn<float,float>(x, x, W(2), W(3), W(4), W(5), W(6), W(7), qb, kb, vb, t0, Sb, part, stream);
  inorm_k<bf16,float,bf16,1><<<dim3(512), TB, 0, stream>>>(t0, x, W(8), u1);
  run_conv(u1, W(23), W(24), col, part, vb, stream);
  inorm_k<bf16,bf16,bf16,0><<<dim3(512), TB, 0, stream>>>(u1, vb, nullptr, u2);

  // stage B: out_3 = inorm(sa2(y))
  run_attn<float,float>(y, y, W(9), W(10), W(11), W(12), W(13), W(14), qb, kb, vb, t0, Sb, part, stream);
  inorm_k<bf16,float,bf16,1><<<dim3(512), TB, 0, stream>>>(t0, y, W(15), u3);

  // stage C: top attention (q,k from out_2; v from out_3), residual = y
  run_attn<bf16,bf16>(u2, u3, W(16), W(17), W(18), W(19), W(20), W(21), qb, kb, vb, t0, Sb, part, stream);
  inorm_k<bf16,float,bf16,1><<<dim3(512), TB, 0, stream>>>(t0, y, W(22), u1);   // o1
  inorm_k<bf16,bf16,bf16,0><<<dim3(512), TB, 0, stream>>>(u1, u3, nullptr, u4); // o2
  run_conv(u4, W(25), W(26), col, part, vb, stream);
  inorm_k<bf16,bf16,float,0><<<dim3(512), TB, 0, stream>>>(u4, vb, nullptr, (float*)d_out);
}

// Round 5
// 727.953 us; speedup vs baseline: 1.4086x; 1.0735x over previous
//
#include <hip/hip_runtime.h>
#include <hip/hip_bf16.h>

typedef __hip_bfloat16 bf16;
typedef __attribute__((ext_vector_type(8))) short s8v;   // 8 bf16 = 4 VGPRs
typedef __attribute__((ext_vector_type(4))) short s4v;   // 4 bf16
typedef __attribute__((ext_vector_type(4))) float f4v;

#define NPIX 4096
#define CDIM 256

// ---- async global->LDS, 16B per lane (dest = wave-uniform base + lane*16) ---
typedef __attribute__((address_space(1))) const unsigned int g_u32;
typedef __attribute__((address_space(3))) unsigned int l_u32;
__device__ __forceinline__ void glds16(const void* g, void* l) {
  __builtin_amdgcn_global_load_lds((g_u32*)g, (l_u32*)l, 16, 0, 0);
}

// ---- 8-element loaders -> bf16x8 (s8v) --------------------------------------
__device__ inline s8v ld8(const bf16* p) { return *(const s8v*)p; }
__device__ inline s8v ld8(const float* p) {
  float4 f0 = *(const float4*)p;
  float4 f1 = *(const float4*)(p + 4);
  s8v r; bf16* e = (bf16*)&r;
  e[0] = __float2bfloat16(f0.x); e[1] = __float2bfloat16(f0.y);
  e[2] = __float2bfloat16(f0.z); e[3] = __float2bfloat16(f0.w);
  e[4] = __float2bfloat16(f1.x); e[5] = __float2bfloat16(f1.y);
  e[6] = __float2bfloat16(f1.z); e[7] = __float2bfloat16(f1.w);
  return r;
}

// ---------------------------------------------------------------------------
// m97-class GEMM: Cpart[z] = A[128-tile] * B^T-tile, fp32 partials, split-K.
// A: [M][K] k-contig bf16.  B: [N][K] k-contig bf16.  C: [M][N] fp32 at z*M*N.
// Tile 128x128, BK=32, 256 threads = 4 waves (2x2), 4x4 16x16x32 acc per wave.
// blockIdx: x = n-tile (N/128), y = m-tile (M/128), z = K-slice (nchunk each).
// ---------------------------------------------------------------------------
__global__ __launch_bounds__(256) void gemm128(
    const bf16* __restrict__ A, const bf16* __restrict__ Bm,
    float* __restrict__ Cp, int N, int K, int nchunk)
{
  __shared__ bf16 a_s[128 * 32];   // [row][k], NO padding (glds layout)
  __shared__ bf16 b_s[128 * 32];
  const int tid = threadIdx.x;
  const int w = tid >> 6, lane = tid & 63;
  const int l15 = lane & 15, oct = lane >> 4;
  const int wr = w >> 1, wc = w & 1;           // wave quadrant in 128x128
  const int m0 = blockIdx.y * 128, n0 = blockIdx.x * 128;
  const int kc0 = blockIdx.z * nchunk, kc1 = kc0 + nchunk;

  // staging: seg = r*4+w covers tile rows [seg*16, seg*16+16), lane l ->
  // row seg*16 + l/4, k-off (l&3)*8 elems; LDS dest base seg*1024 B (uniform)
  const int srow = lane >> 2, skoff = (lane & 3) * 8;
  const long aRow0 = (long)(m0 + (w << 4) + srow) * K;       // seg = w
  const long aRow1 = (long)(m0 + ((w + 4) << 4) + srow) * K; // seg = w+4
  const long bRow0 = (long)(n0 + (w << 4) + srow) * K;
  const long bRow1 = (long)(n0 + ((w + 4) << 4) + srow) * K;
  bf16* lA0 = a_s + (w) * 512;
  bf16* lA1 = a_s + (w + 4) * 512;
  bf16* lB0 = b_s + (w) * 512;
  bf16* lB1 = b_s + (w + 4) * 512;

  f4v acc[4][4];
  #pragma unroll
  for (int i = 0; i < 4; ++i)
    #pragma unroll
    for (int j = 0; j < 4; ++j) acc[i][j] = (f4v){0.f, 0.f, 0.f, 0.f};

  for (int kc = kc0; kc < kc1; ++kc) {
    const int kb = kc * 32 + skoff;
    glds16(A + aRow0 + kb, lA0);
    glds16(A + aRow1 + kb, lA1);
    glds16(Bm + bRow0 + kb, lB0);
    glds16(Bm + bRow1 + kb, lB1);
    __syncthreads();   // drains vmcnt(0): LDS tiles ready
    s8v af[4], bfv[4];
    #pragma unroll
    for (int st = 0; st < 4; ++st)
      af[st] = *(const s8v*)(a_s + (wr * 64 + st * 16 + l15) * 32 + oct * 8);
    #pragma unroll
    for (int nt = 0; nt < 4; ++nt)
      bfv[nt] = *(const s8v*)(b_s + (wc * 64 + nt * 16 + l15) * 32 + oct * 8);
    #pragma unroll
    for (int st = 0; st < 4; ++st)
      #pragma unroll
      for (int nt = 0; nt < 4; ++nt)
        acc[st][nt] = __builtin_amdgcn_mfma_f32_16x16x32_bf16(af[st], bfv[nt], acc[st][nt], 0, 0, 0);
    __syncthreads();   // all reads done before next chunk's glds overwrite
  }

  // epilogue: D row = oct*4 + r, col = l15 within each 16x16 tile
  float* Cz = Cp + (long)blockIdx.z * ((long)gridDim.y * 128) * N;
  #pragma unroll
  for (int st = 0; st < 4; ++st) {
    const int gm = m0 + wr * 64 + st * 16 + oct * 4;
    #pragma unroll
    for (int nt = 0; nt < 4; ++nt) {
      const int gn = n0 + wc * 64 + nt * 16 + l15;
      #pragma unroll
      for (int r = 0; r < 4; ++r)
        Cz[(long)(gm + r) * N + gn] = acc[st][nt][r];
    }
  }
}

// ---------------------------------------------------------------------------
// Legacy 64x64 GEMM (projections, S-GEMM). TA=1: A[K][M] -> A^T*B.
// ---------------------------------------------------------------------------
template<int TA, int TB, int BIAS, typename TAe, typename TBe>
__global__ __launch_bounds__(256) void gemm_k(
    const TAe* __restrict__ A, const TBe* __restrict__ Bm,
    const float* __restrict__ bias, bf16* __restrict__ Cm,
    int M, int N, int K, long abat, long bbat, long cbat, int nchunk)
{
  __shared__ bf16 a_s[64][40];
  __shared__ bf16 b_s[64][40];
  const int tid = threadIdx.x;
  A  += blockIdx.z * abat;
  Bm += blockIdx.z * bbat;
  Cm += blockIdx.z * cbat;
  const int m0 = blockIdx.y * 64, n0 = blockIdx.x * 64;
  const int w = tid >> 6, lane = tid & 63;
  const int l15 = lane & 15, oct = lane >> 4;

  f4v acc[4];
  #pragma unroll
  for (int i = 0; i < 4; ++i) acc[i] = (f4v){0.f, 0.f, 0.f, 0.f};

  int a_i0, a_i1, b_i0, b_i1;
  if (TA == 0) { a_i0 = tid >> 2; a_i1 = (tid & 3) * 8; }
  else         { a_i0 = tid >> 3; a_i1 = (tid & 7) * 8; }
  if (TB == 0) { b_i0 = tid >> 3; b_i1 = (tid & 7) * 8; }
  else         { b_i0 = tid >> 2; b_i1 = (tid & 3) * 8; }

  s8v pa, pb;
  auto ldA = [&](int kc, s8v& d) {
    if (TA == 0) {
      if (m0 + a_i0 < M) d = ld8(A + (long)(m0 + a_i0) * K + kc * 32 + a_i1);
      else d = (s8v){0,0,0,0,0,0,0,0};
    } else {
      d = ld8(A + (long)(kc * 32 + a_i0) * M + m0 + a_i1);
    }
  };
  auto ldB = [&](int kc, s8v& d) {
    if (TB == 0) d = ld8(Bm + (long)(kc * 32 + b_i0) * N + n0 + b_i1);
    else         d = ld8(Bm + (long)(n0 + b_i0) * K + kc * 32 + b_i1);
  };

  ldA(0, pa); ldB(0, pb);
  for (int kc = 0; kc < nchunk; ++kc) {
    if (TA == 0) {
      *(s8v*)&a_s[a_i0][a_i1] = pa;
    } else {
      const bf16* e = (const bf16*)&pa;
      #pragma unroll
      for (int j = 0; j < 8; ++j) a_s[a_i1 + j][a_i0] = e[j];
    }
    if (TB == 0) {
      const bf16* e = (const bf16*)&pb;
      #pragma unroll
      for (int j = 0; j < 8; ++j) b_s[b_i1 + j][b_i0] = e[j];
    } else {
      *(s8v*)&b_s[b_i0][b_i1] = pb;
    }
    __syncthreads();
    if (kc + 1 < nchunk) { ldA(kc + 1, pa); ldB(kc + 1, pb); }
    s8v af = *(const s8v*)&a_s[w * 16 + l15][oct * 8];
    #pragma unroll
    for (int nt = 0; nt < 4; ++nt) {
      s8v bfr = *(const s8v*)&b_s[nt * 16 + l15][oct * 8];
      acc[nt] = __builtin_amdgcn_mfma_f32_16x16x32_bf16(af, bfr, acc[nt], 0, 0, 0);
    }
    __syncthreads();
  }
  const int gm_base = m0 + w * 16 + oct * 4;
  #pragma unroll
  for (int nt = 0; nt < 4; ++nt) {
    #pragma unroll
    for (int r = 0; r < 4; ++r) {
      int gm = gm_base + r;
      if (gm < M) {
        float vv = acc[nt][r];
        if (BIAS) vv += bias[gm];
        Cm[(long)gm * N + n0 + nt * 16 + l15] = __float2bfloat16(vv);
      }
    }
  }
}

// ---- split-K reducer: out = bf16(sum_s part[s] + bias) ----------------------
template<int BIAS>
__global__ __launch_bounds__(256) void reduce_k(
    const float* __restrict__ part, const float* __restrict__ bias,
    bf16* __restrict__ out, int MN, int N, int nsplit)
{
  const int i4 = (blockIdx.x * 256 + threadIdx.x) * 4;
  float4 s = *(const float4*)(part + i4);
  for (int p = 1; p < nsplit; ++p) {
    float4 t = *(const float4*)(part + (long)p * MN + i4);
    s.x += t.x; s.y += t.y; s.z += t.z; s.w += t.w;
  }
  if (BIAS) { float b = bias[i4 / N]; s.x += b; s.y += b; s.z += b; s.w += b; }
  s4v o; bf16* e = (bf16*)&o;
  e[0] = __float2bfloat16(s.x); e[1] = __float2bfloat16(s.y);
  e[2] = __float2bfloat16(s.z); e[3] = __float2bfloat16(s.w);
  *(s4v*)(out + i4) = o;
}

// ---- fp32 -> bf16 convert (guarded) ----------------------------------------
__global__ __launch_bounds__(256) void cvt_k(const float* __restrict__ in,
                                             bf16* __restrict__ out, int n)
{
  const int i4 = (blockIdx.x * 256 + threadIdx.x) * 4;
  if (i4 >= n) return;
  float4 f = *(const float4*)(in + i4);
  s4v o; bf16* e = (bf16*)&o;
  e[0] = __float2bfloat16(f.x); e[1] = __float2bfloat16(f.y);
  e[2] = __float2bfloat16(f.z); e[3] = __float2bfloat16(f.w);
  *(s4v*)(out + i4) = o;
}

// ---- row softmax over 4096, in place ---------------------------------------
__global__ __launch_bounds__(256) void softmax_k(bf16* __restrict__ S)
{
  __shared__ float red[8];
  const int tid = threadIdx.x;
  bf16* p = S + (long)blockIdx.x * NPIX + tid * 16;
  s8v r0 = *(const s8v*)p;
  s8v r1 = *(const s8v*)(p + 8);
  const bf16* e0 = (const bf16*)&r0;
  const bf16* e1 = (const bf16*)&r1;
  float v[16];
  #pragma unroll
  for (int j = 0; j < 8; ++j) { v[j] = __bfloat162float(e0[j]); v[8 + j] = __bfloat162float(e1[j]); }
  float m = -3.0e38f;
  #pragma unroll
  for (int j = 0; j < 16; ++j) m = fmaxf(m, v[j]);
  #pragma unroll
  for (int s = 32; s; s >>= 1) m = fmaxf(m, __shfl_xor(m, s));
  if ((tid & 63) == 0) red[tid >> 6] = m;
  __syncthreads();
  m = fmaxf(fmaxf(red[0], red[1]), fmaxf(red[2], red[3]));
  float sum = 0.f;
  #pragma unroll
  for (int j = 0; j < 16; ++j) { v[j] = __expf(v[j] - m); sum += v[j]; }
  #pragma unroll
  for (int s = 32; s; s >>= 1) sum += __shfl_xor(sum, s);
  if ((tid & 63) == 0) red[4 + (tid >> 6)] = sum;
  __syncthreads();
  sum = red[4] + red[5] + red[6] + red[7];
  float inv = 1.f / sum;
  s8v o0, o1v;
  bf16* f0 = (bf16*)&o0; bf16* f1 = (bf16*)&o1v;
  #pragma unroll
  for (int j = 0; j < 8; ++j) {
    f0[j] = __float2bfloat16(v[j] * inv);
    f1[j] = __float2bfloat16(v[8 + j] * inv);
  }
  *(s8v*)p = o0; *(s8v*)(p + 8) = o1v;
}

// ---- transposed im2col: colT[n][c*9+j] for 3x3 SAME conv -------------------
__global__ __launch_bounds__(256) void im2colT_k(const bf16* __restrict__ x,
                                                 bf16* __restrict__ colT)
{
  int idx = blockIdx.x * 256 + threadIdx.x;   // n*2304 + kk, 4096*2304 total
  int kk = idx % 2304, n = idx / 2304;
  int c = kk / 9, j = kk - c * 9;
  int h = (n >> 6) + j / 3 - 1;
  int ww = (n & 63) + j % 3 - 1;
  bf16 val = __float2bfloat16(0.f);
  if ((unsigned)h < 64u && (unsigned)ww < 64u) val = x[c * 4096 + h * 64 + ww];
  colT[idx] = val;
}

// ---- 16-elem row load/store helpers ----------------------------------------
__device__ inline void ld16(const bf16* p, float* v) {
  s8v r0 = *(const s8v*)p, r1 = *(const s8v*)(p + 8);
  const bf16* e0 = (const bf16*)&r0; const bf16* e1 = (const bf16*)&r1;
  #pragma unroll
  for (int j = 0; j < 8; ++j) { v[j] = __bfloat162float(e0[j]); v[8 + j] = __bfloat162float(e1[j]); }
}
__device__ inline void ld16(const float* p, float* v) {
  #pragma unroll
  for (int q = 0; q < 4; ++q) {
    float4 f = *(const float4*)(p + q * 4);
    v[q * 4 + 0] = f.x; v[q * 4 + 1] = f.y; v[q * 4 + 2] = f.z; v[q * 4 + 3] = f.w;
  }
}
__device__ inline void st16(bf16* p, const float* v) {
  s8v o0, o1v; bf16* f0 = (bf16*)&o0; bf16* f1 = (bf16*)&o1v;
  #pragma unroll
  for (int j = 0; j < 8; ++j) { f0[j] = __float2bfloat16(v[j]); f1[j] = __float2bfloat16(v[8 + j]); }
  *(s8v*)p = o0; *(s8v*)(p + 8) = o1v;
}
__device__ inline void st16(float* p, const float* v) {
  #pragma unroll
  for (int q = 0; q < 4; ++q) {
    float4 f; f.x = v[q * 4 + 0]; f.y = v[q * 4 + 1]; f.z = v[q * 4 + 2]; f.w = v[q * 4 + 3];
    *(float4*)(p + q * 4) = f;
  }
}

// ---- fused InstanceNorm: out = inorm(g*a + b) per row of 4096 --------------
template<typename TAe, typename TBe, typename TOe, int G>
__global__ __launch_bounds__(256) void inorm_k(
    const TAe* __restrict__ a, const TBe* __restrict__ b,
    const float* __restrict__ g, TOe* __restrict__ out)
{
  __shared__ float red[8];
  const int tid = threadIdx.x;
  const long base = (long)blockIdx.x * NPIX + tid * 16;
  float gv = G ? *g : 1.f;
  float va[16], vbv[16], v[16];
  ld16(a + base, va);
  ld16(b + base, vbv);
  #pragma unroll
  for (int j = 0; j < 16; ++j) v[j] = gv * va[j] + vbv[j];
  float sum = 0.f, sq = 0.f;
  #pragma unroll
  for (int j = 0; j < 16; ++j) { sum += v[j]; sq += v[j] * v[j]; }
  #pragma unroll
  for (int s = 32; s; s >>= 1) { sum += __shfl_xor(sum, s); sq += __shfl_xor(sq, s); }
  if ((tid & 63) == 0) { red[tid >> 6] = sum; red[4 + (tid >> 6)] = sq; }
  __syncthreads();
  sum = red[0] + red[1] + red[2] + red[3];
  sq  = red[4] + red[5] + red[6] + red[7];
  float mean = sum * (1.f / NPIX);
  float var  = fmaxf(sq * (1.f / NPIX) - mean * mean, 0.f);
  float rstd = rsqrtf(var + 1e-5f);
  float o[16];
  #pragma unroll
  for (int j = 0; j < 16; ++j) o[j] = (v[j] - mean) * rstd;
  st16(out + base, o);
}

// ---- host-side helpers ------------------------------------------------------
static const long CN  = (long)CDIM * NPIX;
static const long C8N = (long)32 * NPIX;
static const long MN  = (long)CDIM * NPIX;

template<typename TQK, typename TV>
static void run_attn(const TQK* qksrc, const TV* vsrc,
                     const float* wq, const float* bq,
                     const float* wk, const float* bk,
                     const float* wv, const float* bv,
                     bf16* qb, bf16* kb, bf16* vb, bf16* t0, bf16* Sb, float* part,
                     hipStream_t stream)
{
  dim3 TB(256);
  gemm_k<0,0,1,float,TQK><<<dim3(64,1,2), TB, 0, stream>>>(wq, qksrc, bq, qb, 32,  NPIX, 256, 0L, CN, C8N, 8);
  gemm_k<0,0,1,float,TQK><<<dim3(64,1,2), TB, 0, stream>>>(wk, qksrc, bk, kb, 32,  NPIX, 256, 0L, CN, C8N, 8);
  gemm_k<0,0,1,float,TV ><<<dim3(64,4,2), TB, 0, stream>>>(wv, vsrc,  bv, vb, 256, NPIX, 256, 0L, CN, CN, 8);
  for (int b = 0; b < 2; ++b) {
    // S[n][m] = sum_d q[d][n] k[d][m]  (A^T * B, K=32)
    gemm_k<1,0,0,bf16,bf16><<<dim3(64,64,1), TB, 0, stream>>>(qb + b * C8N, kb + b * C8N,
                                                              nullptr, Sb, NPIX, NPIX, 32, 0L, 0L, 0L, 1);
    softmax_k<<<dim3(NPIX), TB, 0, stream>>>(Sb);
    // O[c][n] = sum_m V[c][m] P[n][m]: A=V [256][4096], B=P [n][m], split-K=8
    gemm128<<<dim3(32,2,8), TB, 0, stream>>>(vb + b * CN, Sb, part, NPIX, NPIX, 16);
    reduce_k<0><<<dim3(1024), TB, 0, stream>>>(part, nullptr, t0 + b * CN, (int)MN, NPIX, 8);
  }
}

static void run_conv(const bf16* src, const float* cw, const float* cb,
                     bf16* colT, bf16* wcvt, float* part, bf16* dst, hipStream_t stream)
{
  dim3 TB(256);
  // 256*2304 = 589824 weights, 4 elems/thread -> 576 blocks (was 2304: OOB!)
  cvt_k<<<dim3(576), TB, 0, stream>>>(cw, wcvt, 589824);
  for (int b = 0; b < 2; ++b) {
    im2colT_k<<<dim3(36864), TB, 0, stream>>>(src + b * CN, colT);
    // K = 2304 = 72 chunks, split-K=8 -> 9 chunks per slice
    gemm128<<<dim3(32,2,8), TB, 0, stream>>>(wcvt, colT, part, NPIX, 2304, 9);
    reduce_k<1><<<dim3(1024), TB, 0, stream>>>(part, cb, dst + b * CN, (int)MN, NPIX, 8);
  }
}

// ---------------------------------------------------------------------------
extern "C" void kernel_launch(void* const* d_in, const int* in_sizes, int n_in,
                              void* d_out, int out_size, void* d_ws, size_t ws_size,
                              hipStream_t stream)
{
  (void)in_sizes; (void)n_in; (void)out_size; (void)ws_size;
  const float* x = (const float*)d_in[0];
  const float* y = (const float*)d_in[1];
  auto W = [&](int i) { return (const float*)d_in[i]; };

  char* wp = (char*)d_ws;
  auto take = [&](size_t nbytes) { char* p = wp; wp += (nbytes + 255) & ~(size_t)255; return p; };
  bf16* qb   = (bf16*)take(2 * C8N * 2);
  bf16* kb   = (bf16*)take(2 * C8N * 2);
  bf16* vb   = (bf16*)take(2 * CN * 2);               // V / conv output
  bf16* t0   = (bf16*)take(2 * CN * 2);               // attention O
  bf16* u1   = (bf16*)take(2 * CN * 2);               // out_1 / top o1
  bf16* u2   = (bf16*)take(2 * CN * 2);               // out_2
  bf16* u3   = (bf16*)take(2 * CN * 2);               // out_3
  bf16* u4   = (bf16*)take(2 * CN * 2);               // top o2
  bf16* Sb   = (bf16*)take((size_t)NPIX * NPIX * 2);  // scores / im2colT (aliased)
  bf16* colT = Sb;                                    // never live together
  bf16* wcvt = (bf16*)take((size_t)2304 * 256 * 2);   // bf16 conv weights
  float* part = (float*)take((size_t)8 * MN * 4);     // split-K fp32 partials

  dim3 TB(256);

  // stage A: out_1 = inorm(sa1(x)); out_2 = inorm(out_1 + conv1(out_1))
  run_attn<float,float>(x, x, W(2), W(3), W(4), W(5), W(6), W(7), qb, kb, vb, t0, Sb, part, stream);
  inorm_k<bf16,float,bf16,1><<<dim3(512), TB, 0, stream>>>(t0, x, W(8), u1);
  run_conv(u1, W(23), W(24), colT, wcvt, part, vb, stream);
  inorm_k<bf16,bf16,bf16,0><<<dim3(512), TB, 0, stream>>>(u1, vb, nullptr, u2);

  // stage B: out_3 = inorm(sa2(y))
  run_attn<float,float>(y, y, W(9), W(10), W(11), W(12), W(13), W(14), qb, kb, vb, t0, Sb, part, stream);
  inorm_k<bf16,float,bf16,1><<<dim3(512), TB, 0, stream>>>(t0, y, W(15), u3);

  // stage C: top attention (q,k from out_2; v from out_3), residual = y
  run_attn<bf16,bf16>(u2, u3, W(16), W(17), W(18), W(19), W(20), W(21), qb, kb, vb, t0, Sb, part, stream);
  inorm_k<bf16,float,bf16,1><<<dim3(512), TB, 0, stream>>>(t0, y, W(22), u1);   // o1
  inorm_k<bf16,bf16,bf16,0><<<dim3(512), TB, 0, stream>>>(u1, u3, nullptr, u4); // o2
  run_conv(u4, W(25), W(26), colT, wcvt, part, vb, stream);
  inorm_k<bf16,bf16,float,0><<<dim3(512), TB, 0, stream>>>(u4, vb, nullptr, (float*)d_out);
}

// Round 6
// 641.073 us; speedup vs baseline: 1.5995x; 1.1355x over previous
//
#include <hip/hip_runtime.h>
#include <hip/hip_bf16.h>

typedef __hip_bfloat16 bf16;
typedef __attribute__((ext_vector_type(8))) short s8v;   // 8 bf16 = 4 VGPRs
typedef __attribute__((ext_vector_type(4))) short s4v;   // 4 bf16
typedef __attribute__((ext_vector_type(4))) float f4v;

#define NPIX 4096
#define CDIM 256
#define MN_ELEMS (1 << 20)        // CDIM * NPIX

// ---- async global->LDS, 16B per lane (dest = wave-uniform base + lane*16) ---
typedef __attribute__((address_space(1))) const unsigned int g_u32;
typedef __attribute__((address_space(3))) unsigned int l_u32;
__device__ __forceinline__ void glds16(const void* g, void* l) {
  __builtin_amdgcn_global_load_lds((g_u32*)g, (l_u32*)l, 16, 0, 0);
}

// ---- 8-element loaders -> bf16x8 (s8v) --------------------------------------
__device__ inline s8v ld8(const bf16* p) { return *(const s8v*)p; }
__device__ inline s8v ld8(const float* p) {
  float4 f0 = *(const float4*)p;
  float4 f1 = *(const float4*)(p + 4);
  s8v r; bf16* e = (bf16*)&r;
  e[0] = __float2bfloat16(f0.x); e[1] = __float2bfloat16(f0.y);
  e[2] = __float2bfloat16(f0.z); e[3] = __float2bfloat16(f0.w);
  e[4] = __float2bfloat16(f1.x); e[5] = __float2bfloat16(f1.y);
  e[6] = __float2bfloat16(f1.z); e[7] = __float2bfloat16(f1.w);
  return r;
}

// ---------------------------------------------------------------------------
// m97-class GEMM, batched split-K: z = batch*nsplit + slice.
// A: [M][K] k-contig bf16 (+ b*abat).  B: [N][K] k-contig bf16 (+ b*bbat).
// Cp partials: fp32 at z*M*N (batch-major).  Tile 128x128, BK=32, 4 waves.
// ---------------------------------------------------------------------------
__global__ __launch_bounds__(256) void gemm128(
    const bf16* __restrict__ A, const bf16* __restrict__ Bm,
    float* __restrict__ Cp, int N, int K, int nchunk, int nsplit,
    long abat, long bbat)
{
  __shared__ bf16 a_s[128 * 32];   // [row][k], NO padding (glds layout)
  __shared__ bf16 b_s[128 * 32];
  const int tid = threadIdx.x;
  const int z = blockIdx.z;
  const int bb = z / nsplit, ks = z - bb * nsplit;
  A  += bb * abat;
  Bm += bb * bbat;
  const int w = tid >> 6, lane = tid & 63;
  const int l15 = lane & 15, oct = lane >> 4;
  const int wr = w >> 1, wc = w & 1;           // wave quadrant in 128x128
  const int m0 = blockIdx.y * 128, n0 = blockIdx.x * 128;
  const int kc0 = ks * nchunk, kc1 = kc0 + nchunk;

  const int srow = lane >> 2, skoff = (lane & 3) * 8;
  const long aRow0 = (long)(m0 + (w << 4) + srow) * K;       // seg = w
  const long aRow1 = (long)(m0 + ((w + 4) << 4) + srow) * K; // seg = w+4
  const long bRow0 = (long)(n0 + (w << 4) + srow) * K;
  const long bRow1 = (long)(n0 + ((w + 4) << 4) + srow) * K;
  bf16* lA0 = a_s + (w) * 512;
  bf16* lA1 = a_s + (w + 4) * 512;
  bf16* lB0 = b_s + (w) * 512;
  bf16* lB1 = b_s + (w + 4) * 512;

  f4v acc[4][4];
  #pragma unroll
  for (int i = 0; i < 4; ++i)
    #pragma unroll
    for (int j = 0; j < 4; ++j) acc[i][j] = (f4v){0.f, 0.f, 0.f, 0.f};

  for (int kc = kc0; kc < kc1; ++kc) {
    const int kb = kc * 32 + skoff;
    glds16(A + aRow0 + kb, lA0);
    glds16(A + aRow1 + kb, lA1);
    glds16(Bm + bRow0 + kb, lB0);
    glds16(Bm + bRow1 + kb, lB1);
    __syncthreads();   // drains vmcnt(0): LDS tiles ready
    s8v af[4], bfv[4];
    #pragma unroll
    for (int st = 0; st < 4; ++st)
      af[st] = *(const s8v*)(a_s + (wr * 64 + st * 16 + l15) * 32 + oct * 8);
    #pragma unroll
    for (int nt = 0; nt < 4; ++nt)
      bfv[nt] = *(const s8v*)(b_s + (wc * 64 + nt * 16 + l15) * 32 + oct * 8);
    #pragma unroll
    for (int st = 0; st < 4; ++st)
      #pragma unroll
      for (int nt = 0; nt < 4; ++nt)
        acc[st][nt] = __builtin_amdgcn_mfma_f32_16x16x32_bf16(af[st], bfv[nt], acc[st][nt], 0, 0, 0);
    __syncthreads();
  }

  // epilogue: D row = oct*4 + r, col = l15 within each 16x16 tile
  float* Cz = Cp + (long)z * ((long)gridDim.y * 128) * N;
  #pragma unroll
  for (int st = 0; st < 4; ++st) {
    const int gm = m0 + wr * 64 + st * 16 + oct * 4;
    #pragma unroll
    for (int nt = 0; nt < 4; ++nt) {
      const int gn = n0 + wc * 64 + nt * 16 + l15;
      #pragma unroll
      for (int r = 0; r < 4; ++r)
        Cz[(long)(gm + r) * N + gn] = acc[st][nt][r];
    }
  }
}

// ---------------------------------------------------------------------------
// Legacy 64x64 GEMM (projections, S-GEMM). TA=1: A[K][M] -> A^T*B.
// ---------------------------------------------------------------------------
template<int TA, int TB, int BIAS, typename TAe, typename TBe>
__global__ __launch_bounds__(256) void gemm_k(
    const TAe* __restrict__ A, const TBe* __restrict__ Bm,
    const float* __restrict__ bias, bf16* __restrict__ Cm,
    int M, int N, int K, long abat, long bbat, long cbat, int nchunk)
{
  __shared__ bf16 a_s[64][40];
  __shared__ bf16 b_s[64][40];
  const int tid = threadIdx.x;
  A  += blockIdx.z * abat;
  Bm += blockIdx.z * bbat;
  Cm += blockIdx.z * cbat;
  const int m0 = blockIdx.y * 64, n0 = blockIdx.x * 64;
  const int w = tid >> 6, lane = tid & 63;
  const int l15 = lane & 15, oct = lane >> 4;

  f4v acc[4];
  #pragma unroll
  for (int i = 0; i < 4; ++i) acc[i] = (f4v){0.f, 0.f, 0.f, 0.f};

  int a_i0, a_i1, b_i0, b_i1;
  if (TA == 0) { a_i0 = tid >> 2; a_i1 = (tid & 3) * 8; }
  else         { a_i0 = tid >> 3; a_i1 = (tid & 7) * 8; }
  if (TB == 0) { b_i0 = tid >> 3; b_i1 = (tid & 7) * 8; }
  else         { b_i0 = tid >> 2; b_i1 = (tid & 3) * 8; }

  s8v pa, pb;
  auto ldA = [&](int kc, s8v& d) {
    if (TA == 0) {
      if (m0 + a_i0 < M) d = ld8(A + (long)(m0 + a_i0) * K + kc * 32 + a_i1);
      else d = (s8v){0,0,0,0,0,0,0,0};
    } else {
      d = ld8(A + (long)(kc * 32 + a_i0) * M + m0 + a_i1);
    }
  };
  auto ldB = [&](int kc, s8v& d) {
    if (TB == 0) d = ld8(Bm + (long)(kc * 32 + b_i0) * N + n0 + b_i1);
    else         d = ld8(Bm + (long)(n0 + b_i0) * K + kc * 32 + b_i1);
  };

  ldA(0, pa); ldB(0, pb);
  for (int kc = 0; kc < nchunk; ++kc) {
    if (TA == 0) {
      *(s8v*)&a_s[a_i0][a_i1] = pa;
    } else {
      const bf16* e = (const bf16*)&pa;
      #pragma unroll
      for (int j = 0; j < 8; ++j) a_s[a_i1 + j][a_i0] = e[j];
    }
    if (TB == 0) {
      const bf16* e = (const bf16*)&pb;
      #pragma unroll
      for (int j = 0; j < 8; ++j) b_s[b_i1 + j][b_i0] = e[j];
    } else {
      *(s8v*)&b_s[b_i0][b_i1] = pb;
    }
    __syncthreads();
    if (kc + 1 < nchunk) { ldA(kc + 1, pa); ldB(kc + 1, pb); }
    s8v af = *(const s8v*)&a_s[w * 16 + l15][oct * 8];
    #pragma unroll
    for (int nt = 0; nt < 4; ++nt) {
      s8v bfr = *(const s8v*)&b_s[nt * 16 + l15][oct * 8];
      acc[nt] = __builtin_amdgcn_mfma_f32_16x16x32_bf16(af, bfr, acc[nt], 0, 0, 0);
    }
    __syncthreads();
  }
  const int gm_base = m0 + w * 16 + oct * 4;
  #pragma unroll
  for (int nt = 0; nt < 4; ++nt) {
    #pragma unroll
    for (int r = 0; r < 4; ++r) {
      int gm = gm_base + r;
      if (gm < M) {
        float vv = acc[nt][r];
        if (BIAS) vv += bias[gm];
        Cm[(long)gm * N + n0 + nt * 16 + l15] = __float2bfloat16(vv);
      }
    }
  }
}

// ---- split-K reducer, batch-aware: grid covers nbatch*MN elems --------------
// part layout: [batch][slice][MN]; out: [batch][MN] contiguous. MN = 1<<20.
template<int BIAS>
__global__ __launch_bounds__(256) void reduce_k(
    const float* __restrict__ part, const float* __restrict__ bias,
    bf16* __restrict__ out, int nsplit)
{
  const int g4 = (blockIdx.x * 256 + threadIdx.x) * 4;
  const int b = g4 >> 20, i = g4 & (MN_ELEMS - 1);
  const float* p0 = part + (long)b * nsplit * MN_ELEMS + i;
  float4 s = *(const float4*)p0;
  for (int p = 1; p < nsplit; ++p) {
    float4 t = *(const float4*)(p0 + (long)p * MN_ELEMS);
    s.x += t.x; s.y += t.y; s.z += t.z; s.w += t.w;
  }
  if (BIAS) { float bv = bias[i >> 12]; s.x += bv; s.y += bv; s.z += bv; s.w += bv; }
  s4v o; bf16* e = (bf16*)&o;
  e[0] = __float2bfloat16(s.x); e[1] = __float2bfloat16(s.y);
  e[2] = __float2bfloat16(s.z); e[3] = __float2bfloat16(s.w);
  *(s4v*)(out + g4) = o;
}

// ---- fp32 -> bf16 convert (guarded) ----------------------------------------
__global__ __launch_bounds__(256) void cvt_k(const float* __restrict__ in,
                                             bf16* __restrict__ out, int n)
{
  const int i4 = (blockIdx.x * 256 + threadIdx.x) * 4;
  if (i4 >= n) return;
  float4 f = *(const float4*)(in + i4);
  s4v o; bf16* e = (bf16*)&o;
  e[0] = __float2bfloat16(f.x); e[1] = __float2bfloat16(f.y);
  e[2] = __float2bfloat16(f.z); e[3] = __float2bfloat16(f.w);
  *(s4v*)(out + i4) = o;
}

// ---- row softmax over 4096, in place (grid = #rows) ------------------------
__global__ __launch_bounds__(256) void softmax_k(bf16* __restrict__ S)
{
  __shared__ float red[8];
  const int tid = threadIdx.x;
  bf16* p = S + (long)blockIdx.x * NPIX + tid * 16;
  s8v r0 = *(const s8v*)p;
  s8v r1 = *(const s8v*)(p + 8);
  const bf16* e0 = (const bf16*)&r0;
  const bf16* e1 = (const bf16*)&r1;
  float v[16];
  #pragma unroll
  for (int j = 0; j < 8; ++j) { v[j] = __bfloat162float(e0[j]); v[8 + j] = __bfloat162float(e1[j]); }
  float m = -3.0e38f;
  #pragma unroll
  for (int j = 0; j < 16; ++j) m = fmaxf(m, v[j]);
  #pragma unroll
  for (int s = 32; s; s >>= 1) m = fmaxf(m, __shfl_xor(m, s));
  if ((tid & 63) == 0) red[tid >> 6] = m;
  __syncthreads();
  m = fmaxf(fmaxf(red[0], red[1]), fmaxf(red[2], red[3]));
  float sum = 0.f;
  #pragma unroll
  for (int j = 0; j < 16; ++j) { v[j] = __expf(v[j] - m); sum += v[j]; }
  #pragma unroll
  for (int s = 32; s; s >>= 1) sum += __shfl_xor(sum, s);
  if ((tid & 63) == 0) red[4 + (tid >> 6)] = sum;
  __syncthreads();
  sum = red[4] + red[5] + red[6] + red[7];
  float inv = 1.f / sum;
  s8v o0, o1v;
  bf16* f0 = (bf16*)&o0; bf16* f1 = (bf16*)&o1v;
  #pragma unroll
  for (int j = 0; j < 8; ++j) {
    f0[j] = __float2bfloat16(v[j] * inv);
    f1[j] = __float2bfloat16(v[8 + j] * inv);
  }
  *(s8v*)p = o0; *(s8v*)(p + 8) = o1v;
}

// ---- transposed im2col: colT[n][c*9+j], batch = blockIdx.y -----------------
__global__ __launch_bounds__(256) void im2colT_k(const bf16* __restrict__ x,
                                                 bf16* __restrict__ colT)
{
  x    += (long)blockIdx.y * CDIM * NPIX;
  colT += (long)blockIdx.y * 2304 * NPIX;
  int idx = blockIdx.x * 256 + threadIdx.x;   // n*2304 + kk, 4096*2304 total
  int kk = idx % 2304, n = idx / 2304;
  int c = kk / 9, j = kk - c * 9;
  int h = (n >> 6) + j / 3 - 1;
  int ww = (n & 63) + j % 3 - 1;
  bf16 val = __float2bfloat16(0.f);
  if ((unsigned)h < 64u && (unsigned)ww < 64u) val = x[c * 4096 + h * 64 + ww];
  colT[idx] = val;
}

// ---- 16-elem row load/store helpers ----------------------------------------
__device__ inline void ld16(const bf16* p, float* v) {
  s8v r0 = *(const s8v*)p, r1 = *(const s8v*)(p + 8);
  const bf16* e0 = (const bf16*)&r0; const bf16* e1 = (const bf16*)&r1;
  #pragma unroll
  for (int j = 0; j < 8; ++j) { v[j] = __bfloat162float(e0[j]); v[8 + j] = __bfloat162float(e1[j]); }
}
__device__ inline void ld16(const float* p, float* v) {
  #pragma unroll
  for (int q = 0; q < 4; ++q) {
    float4 f = *(const float4*)(p + q * 4);
    v[q * 4 + 0] = f.x; v[q * 4 + 1] = f.y; v[q * 4 + 2] = f.z; v[q * 4 + 3] = f.w;
  }
}
__device__ inline void st16(bf16* p, const float* v) {
  s8v o0, o1v; bf16* f0 = (bf16*)&o0; bf16* f1 = (bf16*)&o1v;
  #pragma unroll
  for (int j = 0; j < 8; ++j) { f0[j] = __float2bfloat16(v[j]); f1[j] = __float2bfloat16(v[8 + j]); }
  *(s8v*)p = o0; *(s8v*)(p + 8) = o1v;
}
__device__ inline void st16(float* p, const float* v) {
  #pragma unroll
  for (int q = 0; q < 4; ++q) {
    float4 f; f.x = v[q * 4 + 0]; f.y = v[q * 4 + 1]; f.z = v[q * 4 + 2]; f.w = v[q * 4 + 3];
    *(float4*)(p + q * 4) = f;
  }
}

// ---- fused InstanceNorm: out = inorm(g*a + b) per row of 4096 --------------
template<typename TAe, typename TBe, typename TOe, int G>
__global__ __launch_bounds__(256) void inorm_k(
    const TAe* __restrict__ a, const TBe* __restrict__ b,
    const float* __restrict__ g, TOe* __restrict__ out)
{
  __shared__ float red[8];
  const int tid = threadIdx.x;
  const long base = (long)blockIdx.x * NPIX + tid * 16;
  float gv = G ? *g : 1.f;
  float va[16], vbv[16], v[16];
  ld16(a + base, va);
  ld16(b + base, vbv);
  #pragma unroll
  for (int j = 0; j < 16; ++j) v[j] = gv * va[j] + vbv[j];
  float sum = 0.f, sq = 0.f;
  #pragma unroll
  for (int j = 0; j < 16; ++j) { sum += v[j]; sq += v[j] * v[j]; }
  #pragma unroll
  for (int s = 32; s; s >>= 1) { sum += __shfl_xor(sum, s); sq += __shfl_xor(sq, s); }
  if ((tid & 63) == 0) { red[tid >> 6] = sum; red[4 + (tid >> 6)] = sq; }
  __syncthreads();
  sum = red[0] + red[1] + red[2] + red[3];
  sq  = red[4] + red[5] + red[6] + red[7];
  float mean = sum * (1.f / NPIX);
  float var  = fmaxf(sq * (1.f / NPIX) - mean * mean, 0.f);
  float rstd = rsqrtf(var + 1e-5f);
  float o[16];
  #pragma unroll
  for (int j = 0; j < 16; ++j) o[j] = (v[j] - mean) * rstd;
  st16(out + base, o);
}

// ---- host-side helpers ------------------------------------------------------
static const long CN  = (long)CDIM * NPIX;
static const long C8N = (long)32 * NPIX;
static const long SBAT = (long)NPIX * NPIX;   // S batch stride (elems)

template<typename TQK, typename TV>
static void run_attn(bool batched, const TQK* qksrc, const TV* vsrc,
                     const float* wq, const float* bq,
                     const float* wk, const float* bk,
                     const float* wv, const float* bv,
                     bf16* qb, bf16* kb, bf16* vb, bf16* t0, bf16* Sb, float* part,
                     hipStream_t stream)
{
  dim3 TB(256);
  gemm_k<0,0,1,float,TQK><<<dim3(64,1,2), TB, 0, stream>>>(wq, qksrc, bq, qb, 32,  NPIX, 256, 0L, CN, C8N, 8);
  gemm_k<0,0,1,float,TQK><<<dim3(64,1,2), TB, 0, stream>>>(wk, qksrc, bk, kb, 32,  NPIX, 256, 0L, CN, C8N, 8);
  gemm_k<0,0,1,float,TV ><<<dim3(64,4,2), TB, 0, stream>>>(wv, vsrc,  bv, vb, 256, NPIX, 256, 0L, CN, CN, 8);
  if (batched) {
    // S[n][m] both batches; softmax both; PV z = batch*4 + slice (512 blocks)
    gemm_k<1,0,0,bf16,bf16><<<dim3(64,64,2), TB, 0, stream>>>(qb, kb, nullptr, Sb,
                                                              NPIX, NPIX, 32, C8N, C8N, SBAT, 1);
    softmax_k<<<dim3(2 * NPIX), TB, 0, stream>>>(Sb);
    gemm128<<<dim3(32,2,8), TB, 0, stream>>>(vb, Sb, part, NPIX, NPIX, 32, 4, CN, SBAT);
    reduce_k<0><<<dim3(2048), TB, 0, stream>>>(part, nullptr, t0, 4);
  } else {
    for (int b = 0; b < 2; ++b) {
      gemm_k<1,0,0,bf16,bf16><<<dim3(64,64,1), TB, 0, stream>>>(qb + b * C8N, kb + b * C8N,
                                                                nullptr, Sb, NPIX, NPIX, 32, 0L, 0L, 0L, 1);
      softmax_k<<<dim3(NPIX), TB, 0, stream>>>(Sb);
      gemm128<<<dim3(32,2,8), TB, 0, stream>>>(vb + b * CN, Sb, part, NPIX, NPIX, 16, 8, 0L, 0L);
      reduce_k<0><<<dim3(1024), TB, 0, stream>>>(part, nullptr, t0 + b * CN, 8);
    }
  }
}

static void run_conv(bool batched, const bf16* src, const float* cw, const float* cb,
                     bf16* colT, bf16* wcvt, float* part, bf16* dst, hipStream_t stream)
{
  dim3 TB(256);
  cvt_k<<<dim3(576), TB, 0, stream>>>(cw, wcvt, 589824);  // 256*2304 weights
  if (batched) {
    im2colT_k<<<dim3(36864, 2), TB, 0, stream>>>(src, colT);
    // K = 2304 = 72 chunks, 4 slices x 18 chunks, z = batch*4 + slice
    gemm128<<<dim3(32,2,8), TB, 0, stream>>>(wcvt, colT, part, NPIX, 2304, 18, 4, 0L, 2304L * NPIX);
    reduce_k<1><<<dim3(2048), TB, 0, stream>>>(part, cb, dst, 4);
  } else {
    for (int b = 0; b < 2; ++b) {
      im2colT_k<<<dim3(36864, 1), TB, 0, stream>>>(src + b * CN, colT);
      gemm128<<<dim3(32,2,8), TB, 0, stream>>>(wcvt, colT, part, NPIX, 2304, 9, 8, 0L, 0L);
      reduce_k<1><<<dim3(1024), TB, 0, stream>>>(part, cb, dst + b * CN, 8);
    }
  }
}

// ---------------------------------------------------------------------------
extern "C" void kernel_launch(void* const* d_in, const int* in_sizes, int n_in,
                              void* d_out, int out_size, void* d_ws, size_t ws_size,
                              hipStream_t stream)
{
  (void)in_sizes; (void)n_in; (void)out_size;
  const float* x = (const float*)d_in[0];
  const float* y = (const float*)d_in[1];
  auto W = [&](int i) { return (const float*)d_in[i]; };

  // batched path needs S for both batches (67 MB): ~122.2 MB total.
  const size_t need_batched = 130u * 1024 * 1024;
  const bool batched = ws_size >= need_batched;

  char* wp = (char*)d_ws;
  auto take = [&](size_t nbytes) { char* p = wp; wp += (nbytes + 255) & ~(size_t)255; return p; };
  bf16* qb   = (bf16*)take(2 * C8N * 2);
  bf16* kb   = (bf16*)take(2 * C8N * 2);
  bf16* vb   = (bf16*)take(2 * CN * 2);               // V / conv output
  bf16* t0   = (bf16*)take(2 * CN * 2);               // attention O
  bf16* u1   = (bf16*)take(2 * CN * 2);               // out_1 / top o1
  bf16* u2   = (bf16*)take(2 * CN * 2);               // out_2
  bf16* u3   = (bf16*)take(2 * CN * 2);               // out_3
  bf16* u4   = (bf16*)take(2 * CN * 2);               // top o2
  bf16* Sb   = (bf16*)take((batched ? 2u : 1u) * (size_t)SBAT * 2);  // scores / im2colT
  bf16* colT = Sb;                                    // aliased: never live together
  bf16* wcvt = (bf16*)take((size_t)2304 * 256 * 2);   // bf16 conv weights
  float* part = (float*)take((size_t)8 * MN_ELEMS * 4); // split-K fp32 partials (32 MB)

  dim3 TB(256);

  // stage A: out_1 = inorm(sa1(x)); out_2 = inorm(out_1 + conv1(out_1))
  run_attn<float,float>(batched, x, x, W(2), W(3), W(4), W(5), W(6), W(7), qb, kb, vb, t0, Sb, part, stream);
  inorm_k<bf16,float,bf16,1><<<dim3(512), TB, 0, stream>>>(t0, x, W(8), u1);
  run_conv(batched, u1, W(23), W(24), colT, wcvt, part, vb, stream);
  inorm_k<bf16,bf16,bf16,0><<<dim3(512), TB, 0, stream>>>(u1, vb, nullptr, u2);

  // stage B: out_3 = inorm(sa2(y))
  run_attn<float,float>(batched, y, y, W(9), W(10), W(11), W(12), W(13), W(14), qb, kb, vb, t0, Sb, part, stream);
  inorm_k<bf16,float,bf16,1><<<dim3(512), TB, 0, stream>>>(t0, y, W(15), u3);

  // stage C: top attention (q,k from out_2; v from out_3), residual = y
  run_attn<bf16,bf16>(batched, u2, u3, W(16), W(17), W(18), W(19), W(20), W(21), qb, kb, vb, t0, Sb, part, stream);
  inorm_k<bf16,float,bf16,1><<<dim3(512), TB, 0, stream>>>(t0, y, W(22), u1);   // o1
  inorm_k<bf16,bf16,bf16,0><<<dim3(512), TB, 0, stream>>>(u1, u3, nullptr, u4); // o2
  run_conv(batched, u4, W(25), W(26), colT, wcvt, part, vb, stream);
  inorm_k<bf16,bf16,float,0><<<dim3(512), TB, 0, stream>>>(u4, vb, nullptr, (float*)d_out);
}

// Round 7
// 607.526 us; speedup vs baseline: 1.6879x; 1.0552x over previous
//
#include <hip/hip_runtime.h>
#include <hip/hip_bf16.h>

typedef __hip_bfloat16 bf16;
typedef __attribute__((ext_vector_type(8))) short s8v;   // 8 bf16 = 4 VGPRs
typedef __attribute__((ext_vector_type(4))) short s4v;   // 4 bf16
typedef __attribute__((ext_vector_type(4))) float f4v;

#define NPIX 4096
#define CDIM 256
#define MN_ELEMS (1 << 20)        // CDIM * NPIX

// ---- async global->LDS, 16B per lane (dest = wave-uniform base + lane*16) ---
typedef __attribute__((address_space(1))) const unsigned int g_u32;
typedef __attribute__((address_space(3))) unsigned int l_u32;
__device__ __forceinline__ void glds16(const void* g, void* l) {
  __builtin_amdgcn_global_load_lds((g_u32*)g, (l_u32*)l, 16, 0, 0);
}

// ---- 8-element loaders -> bf16x8 (s8v) --------------------------------------
__device__ inline s8v ld8(const bf16* p) { return *(const s8v*)p; }
__device__ inline s8v ld8(const float* p) {
  float4 f0 = *(const float4*)p;
  float4 f1 = *(const float4*)(p + 4);
  s8v r; bf16* e = (bf16*)&r;
  e[0] = __float2bfloat16(f0.x); e[1] = __float2bfloat16(f0.y);
  e[2] = __float2bfloat16(f0.z); e[3] = __float2bfloat16(f0.w);
  e[4] = __float2bfloat16(f1.x); e[5] = __float2bfloat16(f1.y);
  e[6] = __float2bfloat16(f1.z); e[7] = __float2bfloat16(f1.w);
  return r;
}

// ---------------------------------------------------------------------------
// m97-class GEMM, batched split-K: z = batch*nsplit + slice.
// A: [M][K] k-contig bf16 (+ b*abat).  B: [N][K] k-contig bf16 (+ b*bbat).
// Cp partials: fp32 at z*M*N.  Tile 128x128, BK=32, 4 waves (2x2).
// ---------------------------------------------------------------------------
__global__ __launch_bounds__(256) void gemm128(
    const bf16* __restrict__ A, const bf16* __restrict__ Bm,
    float* __restrict__ Cp, int N, int K, int nchunk, int nsplit,
    long abat, long bbat)
{
  __shared__ bf16 a_s[128 * 32];   // [row][k], NO padding (glds layout)
  __shared__ bf16 b_s[128 * 32];
  const int tid = threadIdx.x;
  const int z = blockIdx.z;
  const int bb = z / nsplit, ks = z - bb * nsplit;
  A  += bb * abat;
  Bm += bb * bbat;
  const int w = tid >> 6, lane = tid & 63;
  const int l15 = lane & 15, oct = lane >> 4;
  const int wr = w >> 1, wc = w & 1;           // wave quadrant in 128x128
  const int m0 = blockIdx.y * 128, n0 = blockIdx.x * 128;
  const int kc0 = ks * nchunk, kc1 = kc0 + nchunk;

  const int srow = lane >> 2, skoff = (lane & 3) * 8;
  const long aRow0 = (long)(m0 + (w << 4) + srow) * K;       // seg = w
  const long aRow1 = (long)(m0 + ((w + 4) << 4) + srow) * K; // seg = w+4
  const long bRow0 = (long)(n0 + (w << 4) + srow) * K;
  const long bRow1 = (long)(n0 + ((w + 4) << 4) + srow) * K;
  bf16* lA0 = a_s + (w) * 512;
  bf16* lA1 = a_s + (w + 4) * 512;
  bf16* lB0 = b_s + (w) * 512;
  bf16* lB1 = b_s + (w + 4) * 512;

  f4v acc[4][4];
  #pragma unroll
  for (int i = 0; i < 4; ++i)
    #pragma unroll
    for (int j = 0; j < 4; ++j) acc[i][j] = (f4v){0.f, 0.f, 0.f, 0.f};

  for (int kc = kc0; kc < kc1; ++kc) {
    const int kb = kc * 32 + skoff;
    glds16(A + aRow0 + kb, lA0);
    glds16(A + aRow1 + kb, lA1);
    glds16(Bm + bRow0 + kb, lB0);
    glds16(Bm + bRow1 + kb, lB1);
    __syncthreads();   // drains vmcnt(0): LDS tiles ready
    s8v af[4], bfv[4];
    #pragma unroll
    for (int st = 0; st < 4; ++st)
      af[st] = *(const s8v*)(a_s + (wr * 64 + st * 16 + l15) * 32 + oct * 8);
    #pragma unroll
    for (int nt = 0; nt < 4; ++nt)
      bfv[nt] = *(const s8v*)(b_s + (wc * 64 + nt * 16 + l15) * 32 + oct * 8);
    #pragma unroll
    for (int st = 0; st < 4; ++st)
      #pragma unroll
      for (int nt = 0; nt < 4; ++nt)
        acc[st][nt] = __builtin_amdgcn_mfma_f32_16x16x32_bf16(af[st], bfv[nt], acc[st][nt], 0, 0, 0);
    __syncthreads();
  }

  float* Cz = Cp + (long)z * ((long)gridDim.y * 128) * N;
  #pragma unroll
  for (int st = 0; st < 4; ++st) {
    const int gm = m0 + wr * 64 + st * 16 + oct * 4;
    #pragma unroll
    for (int nt = 0; nt < 4; ++nt) {
      const int gn = n0 + wc * 64 + nt * 16 + l15;
      #pragma unroll
      for (int r = 0; r < 4; ++r)
        Cz[(long)(gm + r) * N + gn] = acc[st][nt][r];
    }
  }
}

// ---------------------------------------------------------------------------
// Legacy 64x64 GEMM (projections, S-GEMM). TA=1: A[K][M] -> A^T*B.
// ---------------------------------------------------------------------------
template<int TA, int TB, int BIAS, typename TAe, typename TBe>
__global__ __launch_bounds__(256) void gemm_k(
    const TAe* __restrict__ A, const TBe* __restrict__ Bm,
    const float* __restrict__ bias, bf16* __restrict__ Cm,
    int M, int N, int K, long abat, long bbat, long cbat, int nchunk)
{
  __shared__ bf16 a_s[64][40];
  __shared__ bf16 b_s[64][40];
  const int tid = threadIdx.x;
  A  += blockIdx.z * abat;
  Bm += blockIdx.z * bbat;
  Cm += blockIdx.z * cbat;
  const int m0 = blockIdx.y * 64, n0 = blockIdx.x * 64;
  const int w = tid >> 6, lane = tid & 63;
  const int l15 = lane & 15, oct = lane >> 4;

  f4v acc[4];
  #pragma unroll
  for (int i = 0; i < 4; ++i) acc[i] = (f4v){0.f, 0.f, 0.f, 0.f};

  int a_i0, a_i1, b_i0, b_i1;
  if (TA == 0) { a_i0 = tid >> 2; a_i1 = (tid & 3) * 8; }
  else         { a_i0 = tid >> 3; a_i1 = (tid & 7) * 8; }
  if (TB == 0) { b_i0 = tid >> 3; b_i1 = (tid & 7) * 8; }
  else         { b_i0 = tid >> 2; b_i1 = (tid & 3) * 8; }

  s8v pa, pb;
  auto ldA = [&](int kc, s8v& d) {
    if (TA == 0) {
      if (m0 + a_i0 < M) d = ld8(A + (long)(m0 + a_i0) * K + kc * 32 + a_i1);
      else d = (s8v){0,0,0,0,0,0,0,0};
    } else {
      d = ld8(A + (long)(kc * 32 + a_i0) * M + m0 + a_i1);
    }
  };
  auto ldB = [&](int kc, s8v& d) {
    if (TB == 0) d = ld8(Bm + (long)(kc * 32 + b_i0) * N + n0 + b_i1);
    else         d = ld8(Bm + (long)(n0 + b_i0) * K + kc * 32 + b_i1);
  };

  ldA(0, pa); ldB(0, pb);
  for (int kc = 0; kc < nchunk; ++kc) {
    if (TA == 0) {
      *(s8v*)&a_s[a_i0][a_i1] = pa;
    } else {
      const bf16* e = (const bf16*)&pa;
      #pragma unroll
      for (int j = 0; j < 8; ++j) a_s[a_i1 + j][a_i0] = e[j];
    }
    if (TB == 0) {
      const bf16* e = (const bf16*)&pb;
      #pragma unroll
      for (int j = 0; j < 8; ++j) b_s[b_i1 + j][b_i0] = e[j];
    } else {
      *(s8v*)&b_s[b_i0][b_i1] = pb;
    }
    __syncthreads();
    if (kc + 1 < nchunk) { ldA(kc + 1, pa); ldB(kc + 1, pb); }
    s8v af = *(const s8v*)&a_s[w * 16 + l15][oct * 8];
    #pragma unroll
    for (int nt = 0; nt < 4; ++nt) {
      s8v bfr = *(const s8v*)&b_s[nt * 16 + l15][oct * 8];
      acc[nt] = __builtin_amdgcn_mfma_f32_16x16x32_bf16(af, bfr, acc[nt], 0, 0, 0);
    }
    __syncthreads();
  }
  const int gm_base = m0 + w * 16 + oct * 4;
  #pragma unroll
  for (int nt = 0; nt < 4; ++nt) {
    #pragma unroll
    for (int r = 0; r < 4; ++r) {
      int gm = gm_base + r;
      if (gm < M) {
        float vv = acc[nt][r];
        if (BIAS) vv += bias[gm];
        Cm[(long)gm * N + n0 + nt * 16 + l15] = __float2bfloat16(vv);
      }
    }
  }
}

// ---- split-K reducer, batch-aware -------------------------------------------
template<int BIAS>
__global__ __launch_bounds__(256) void reduce_k(
    const float* __restrict__ part, const float* __restrict__ bias,
    bf16* __restrict__ out, int nsplit)
{
  const int g4 = (blockIdx.x * 256 + threadIdx.x) * 4;
  const int b = g4 >> 20, i = g4 & (MN_ELEMS - 1);
  const float* p0 = part + (long)b * nsplit * MN_ELEMS + i;
  float4 s = *(const float4*)p0;
  for (int p = 1; p < nsplit; ++p) {
    float4 t = *(const float4*)(p0 + (long)p * MN_ELEMS);
    s.x += t.x; s.y += t.y; s.z += t.z; s.w += t.w;
  }
  if (BIAS) { float bv = bias[i >> 12]; s.x += bv; s.y += bv; s.z += bv; s.w += bv; }
  s4v o; bf16* e = (bf16*)&o;
  e[0] = __float2bfloat16(s.x); e[1] = __float2bfloat16(s.y);
  e[2] = __float2bfloat16(s.z); e[3] = __float2bfloat16(s.w);
  *(s4v*)(out + g4) = o;
}

// ---- conv weight convert + K-reorder: wcvt[o][j*256+c] = cw[o][c][j] --------
__global__ __launch_bounds__(256) void cvtw_k(const float* __restrict__ in,
                                              bf16* __restrict__ out)
{
  int idx = blockIdx.x * 256 + threadIdx.x;   // o*2304 + j*256 + c
  int o = idx / 2304, r = idx % 2304;
  int j = r >> 8, c = r & 255;
  out[idx] = __float2bfloat16(in[(o * 256 + c) * 9 + j]);
}

// ---- row softmax over 4096, in place (grid = #rows) ------------------------
__global__ __launch_bounds__(256) void softmax_k(bf16* __restrict__ S)
{
  __shared__ float red[8];
  const int tid = threadIdx.x;
  bf16* p = S + (long)blockIdx.x * NPIX + tid * 16;
  s8v r0 = *(const s8v*)p;
  s8v r1 = *(const s8v*)(p + 8);
  const bf16* e0 = (const bf16*)&r0;
  const bf16* e1 = (const bf16*)&r1;
  float v[16];
  #pragma unroll
  for (int j = 0; j < 8; ++j) { v[j] = __bfloat162float(e0[j]); v[8 + j] = __bfloat162float(e1[j]); }
  float m = -3.0e38f;
  #pragma unroll
  for (int j = 0; j < 16; ++j) m = fmaxf(m, v[j]);
  #pragma unroll
  for (int s = 32; s; s >>= 1) m = fmaxf(m, __shfl_xor(m, s));
  if ((tid & 63) == 0) red[tid >> 6] = m;
  __syncthreads();
  m = fmaxf(fmaxf(red[0], red[1]), fmaxf(red[2], red[3]));
  float sum = 0.f;
  #pragma unroll
  for (int j = 0; j < 16; ++j) { v[j] = __expf(v[j] - m); sum += v[j]; }
  #pragma unroll
  for (int s = 32; s; s >>= 1) sum += __shfl_xor(sum, s);
  if ((tid & 63) == 0) red[4 + (tid >> 6)] = sum;
  __syncthreads();
  sum = red[4] + red[5] + red[6] + red[7];
  float inv = 1.f / sum;
  s8v o0, o1v;
  bf16* f0 = (bf16*)&o0; bf16* f1 = (bf16*)&o1v;
  #pragma unroll
  for (int j = 0; j < 8; ++j) {
    f0[j] = __float2bfloat16(v[j] * inv);
    f1[j] = __float2bfloat16(v[8 + j] * inv);
  }
  *(s8v*)p = o0; *(s8v*)(p + 8) = o1v;
}

// ---------------------------------------------------------------------------
// LDS-transpose im2col, K-reordered: colT[n][j*256+c], j = dy*3+dx.
// Block = (h, c-tile of 64, batch). Stage x[c][h-1..h+1][*] coalesced into
// LDS [3][66][66] (zero borders; c-stride 66 elems = 33 dwords -> conflict-
// free), then write 9 j-planes with lanes along c (b128 reads, 16B stores).
// ---------------------------------------------------------------------------
__global__ __launch_bounds__(256) void im2colT2_k(const bf16* __restrict__ x,
                                                  bf16* __restrict__ colT)
{
  __shared__ bf16 lds[3 * 66 * 66];
  const int tid = threadIdx.x;
  const int h = blockIdx.x, c0 = blockIdx.y * 64;
  x    += (long)blockIdx.z * CDIM * NPIX;
  colT += (long)blockIdx.z * 2304L * NPIX;

  // zero the w-borders (entries 0 and 65 of each [row] line)
  if (tid < 192) {
    int row = tid >> 6, c = tid & 63;
    lds[(row * 66 + 0) * 66 + c] = __float2bfloat16(0.f);
    lds[(row * 66 + 65) * 66 + c] = __float2bfloat16(0.f);
  }
  // stage: lanes along w (coalesced 4B loads); 3 rows x 8 c-groups
  const int w2 = tid & 31, chi = tid >> 5;   // w2: 2 pixels; chi: 0..7
  #pragma unroll
  for (int it = 0; it < 24; ++it) {
    int row = it >> 3, cg = it & 7;
    int c = cg * 8 + chi;
    int hh = h + row - 1;
    unsigned int pix = 0;
    if ((unsigned)hh < 64u)
      pix = *(const unsigned int*)(x + (long)(c0 + c) * 4096 + hh * 64 + w2 * 2);
    const bf16* pp = (const bf16*)&pix;
    lds[(row * 66 + (w2 * 2 + 1)) * 66 + c] = pp[0];
    lds[(row * 66 + (w2 * 2 + 2)) * 66 + c] = pp[1];
  }
  __syncthreads();
  // write: lanes along c (8 c's each via b128); 9 j x 64 w x 64 c
  const int cg8 = tid & 7, wq = tid >> 3;
  #pragma unroll
  for (int j = 0; j < 9; ++j) {
    const int dy = j / 3, dx = j % 3;
    #pragma unroll
    for (int half = 0; half < 2; ++half) {
      int w = wq + half * 32;
      s8v v = *(const s8v*)&lds[(dy * 66 + (w + dx)) * 66 + cg8 * 8];
      *(s8v*)(colT + (long)(h * 64 + w) * 2304 + j * 256 + c0 + cg8 * 8) = v;
    }
  }
}

// ---- 16-elem row load/store helpers ----------------------------------------
__device__ inline void ld16(const bf16* p, float* v) {
  s8v r0 = *(const s8v*)p, r1 = *(const s8v*)(p + 8);
  const bf16* e0 = (const bf16*)&r0; const bf16* e1 = (const bf16*)&r1;
  #pragma unroll
  for (int j = 0; j < 8; ++j) { v[j] = __bfloat162float(e0[j]); v[8 + j] = __bfloat162float(e1[j]); }
}
__device__ inline void ld16(const float* p, float* v) {
  #pragma unroll
  for (int q = 0; q < 4; ++q) {
    float4 f = *(const float4*)(p + q * 4);
    v[q * 4 + 0] = f.x; v[q * 4 + 1] = f.y; v[q * 4 + 2] = f.z; v[q * 4 + 3] = f.w;
  }
}
__device__ inline void st16(bf16* p, const float* v) {
  s8v o0, o1v; bf16* f0 = (bf16*)&o0; bf16* f1 = (bf16*)&o1v;
  #pragma unroll
  for (int j = 0; j < 8; ++j) { f0[j] = __float2bfloat16(v[j]); f1[j] = __float2bfloat16(v[8 + j]); }
  *(s8v*)p = o0; *(s8v*)(p + 8) = o1v;
}
__device__ inline void st16(float* p, const float* v) {
  #pragma unroll
  for (int q = 0; q < 4; ++q) {
    float4 f; f.x = v[q * 4 + 0]; f.y = v[q * 4 + 1]; f.z = v[q * 4 + 2]; f.w = v[q * 4 + 3];
    *(float4*)(p + q * 4) = f;
  }
}

// ---- fused InstanceNorm: out = inorm(g*a + b) per row of 4096 --------------
template<typename TAe, typename TBe, typename TOe, int G>
__global__ __launch_bounds__(256) void inorm_k(
    const TAe* __restrict__ a, const TBe* __restrict__ b,
    const float* __restrict__ g, TOe* __restrict__ out)
{
  __shared__ float red[8];
  const int tid = threadIdx.x;
  const long base = (long)blockIdx.x * NPIX + tid * 16;
  float gv = G ? *g : 1.f;
  float va[16], vbv[16], v[16];
  ld16(a + base, va);
  ld16(b + base, vbv);
  #pragma unroll
  for (int j = 0; j < 16; ++j) v[j] = gv * va[j] + vbv[j];
  float sum = 0.f, sq = 0.f;
  #pragma unroll
  for (int j = 0; j < 16; ++j) { sum += v[j]; sq += v[j] * v[j]; }
  #pragma unroll
  for (int s = 32; s; s >>= 1) { sum += __shfl_xor(sum, s); sq += __shfl_xor(sq, s); }
  if ((tid & 63) == 0) { red[tid >> 6] = sum; red[4 + (tid >> 6)] = sq; }
  __syncthreads();
  sum = red[0] + red[1] + red[2] + red[3];
  sq  = red[4] + red[5] + red[6] + red[7];
  float mean = sum * (1.f / NPIX);
  float var  = fmaxf(sq * (1.f / NPIX) - mean * mean, 0.f);
  float rstd = rsqrtf(var + 1e-5f);
  float o[16];
  #pragma unroll
  for (int j = 0; j < 16; ++j) o[j] = (v[j] - mean) * rstd;
  st16(out + base, o);
}

// ---- host-side helpers ------------------------------------------------------
static const long CN  = (long)CDIM * NPIX;
static const long C8N = (long)32 * NPIX;
static const long SBAT = (long)NPIX * NPIX;   // S batch stride (elems)

template<typename TQK, typename TV>
static void run_attn(int nsp, const TQK* qksrc, const TV* vsrc,
                     const float* wq, const float* bq,
                     const float* wk, const float* bk,
                     const float* wv, const float* bv,
                     bf16* qb, bf16* kb, bf16* vb, bf16* t0, bf16* Sb, float* part,
                     hipStream_t stream)
{
  dim3 TB(256);
  gemm_k<0,0,1,float,TQK><<<dim3(64,1,2), TB, 0, stream>>>(wq, qksrc, bq, qb, 32,  NPIX, 256, 0L, CN, C8N, 8);
  gemm_k<0,0,1,float,TQK><<<dim3(64,1,2), TB, 0, stream>>>(wk, qksrc, bk, kb, 32,  NPIX, 256, 0L, CN, C8N, 8);
  gemm_k<0,0,1,float,TV ><<<dim3(64,4,2), TB, 0, stream>>>(wv, vsrc,  bv, vb, 256, NPIX, 256, 0L, CN, CN, 8);
  // S[n][m] both batches, softmax, PV split-K
  gemm_k<1,0,0,bf16,bf16><<<dim3(64,64,2), TB, 0, stream>>>(qb, kb, nullptr, Sb,
                                                            NPIX, NPIX, 32, C8N, C8N, SBAT, 1);
  softmax_k<<<dim3(2 * NPIX), TB, 0, stream>>>(Sb);
  gemm128<<<dim3(32,2,2*nsp), TB, 0, stream>>>(vb, Sb, part, NPIX, NPIX, 128/nsp, nsp, CN, SBAT);
  reduce_k<0><<<dim3(2048), TB, 0, stream>>>(part, nullptr, t0, nsp);
}

static void run_conv(int nsp, const bf16* src, const float* cw, const float* cb,
                     bf16* colT, bf16* wcvt, float* part, bf16* dst, hipStream_t stream)
{
  dim3 TB(256);
  cvtw_k<<<dim3(2304), TB, 0, stream>>>(cw, wcvt);   // 256*2304 reordered weights
  im2colT2_k<<<dim3(64, 4, 2), TB, 0, stream>>>(src, colT);
  gemm128<<<dim3(32,2,2*nsp), TB, 0, stream>>>(wcvt, colT, part, NPIX, 2304, 72/nsp, nsp, 0L, 2304L * NPIX);
  reduce_k<1><<<dim3(2048), TB, 0, stream>>>(part, cb, dst, nsp);
}

// ---------------------------------------------------------------------------
extern "C" void kernel_launch(void* const* d_in, const int* in_sizes, int n_in,
                              void* d_out, int out_size, void* d_ws, size_t ws_size,
                              hipStream_t stream)
{
  (void)in_sizes; (void)n_in; (void)out_size;
  const float* x = (const float*)d_in[0];
  const float* y = (const float*)d_in[1];
  auto W = [&](int i) { return (const float*)d_in[i]; };

  // split-8 needs 64 MB partials (total ~159 MB); round 6 proved ws >= 130 MB.
  const int nsp = (ws_size >= ((size_t)168 << 20)) ? 8 : 4;

  char* wp = (char*)d_ws;
  auto take = [&](size_t nbytes) { char* p = wp; wp += (nbytes + 255) & ~(size_t)255; return p; };
  bf16* qb   = (bf16*)take(2 * C8N * 2);
  bf16* kb   = (bf16*)take(2 * C8N * 2);
  bf16* vb   = (bf16*)take(2 * CN * 2);               // V / conv output
  bf16* t0   = (bf16*)take(2 * CN * 2);               // attention O
  bf16* u1   = (bf16*)take(2 * CN * 2);               // out_1 / top o1
  bf16* u2   = (bf16*)take(2 * CN * 2);               // out_2
  bf16* u3   = (bf16*)take(2 * CN * 2);               // out_3
  bf16* u4   = (bf16*)take(2 * CN * 2);               // top o2
  bf16* Sb   = (bf16*)take(2 * (size_t)SBAT * 2);     // scores / im2colT (aliased)
  bf16* colT = Sb;                                    // never live together
  bf16* wcvt = (bf16*)take((size_t)2304 * 256 * 2);   // bf16 conv weights (reordered)
  float* part = (float*)take((size_t)(2 * nsp) * MN_ELEMS * 4); // split-K partials

  dim3 TB(256);

  // stage A: out_1 = inorm(sa1(x)); out_2 = inorm(out_1 + conv1(out_1))
  run_attn<float,float>(nsp, x, x, W(2), W(3), W(4), W(5), W(6), W(7), qb, kb, vb, t0, Sb, part, stream);
  inorm_k<bf16,float,bf16,1><<<dim3(512), TB, 0, stream>>>(t0, x, W(8), u1);
  run_conv(nsp, u1, W(23), W(24), colT, wcvt, part, vb, stream);
  inorm_k<bf16,bf16,bf16,0><<<dim3(512), TB, 0, stream>>>(u1, vb, nullptr, u2);

  // stage B: out_3 = inorm(sa2(y))
  run_attn<float,float>(nsp, y, y, W(9), W(10), W(11), W(12), W(13), W(14), qb, kb, vb, t0, Sb, part, stream);
  inorm_k<bf16,float,bf16,1><<<dim3(512), TB, 0, stream>>>(t0, y, W(15), u3);

  // stage C: top attention (q,k from out_2; v from out_3), residual = y
  run_attn<bf16,bf16>(nsp, u2, u3, W(16), W(17), W(18), W(19), W(20), W(21), qb, kb, vb, t0, Sb, part, stream);
  inorm_k<bf16,float,bf16,1><<<dim3(512), TB, 0, stream>>>(t0, y, W(22), u1);   // o1
  inorm_k<bf16,bf16,bf16,0><<<dim3(512), TB, 0, stream>>>(u1, u3, nullptr, u4); // o2
  run_conv(nsp, u4, W(25), W(26), colT, wcvt, part, vb, stream);
  inorm_k<bf16,bf16,float,0><<<dim3(512), TB, 0, stream>>>(u4, vb, nullptr, (float*)d_out);
}

// Round 8
// 515.272 us; speedup vs baseline: 1.9900x; 1.1790x over previous
//
#include <hip/hip_runtime.h>
#include <hip/hip_bf16.h>

typedef __hip_bfloat16 bf16;
typedef __attribute__((ext_vector_type(8))) short s8v;   // 8 bf16 = 4 VGPRs
typedef __attribute__((ext_vector_type(4))) short s4v;   // 4 bf16
typedef __attribute__((ext_vector_type(4))) float f4v;

#define NPIX 4096
#define CDIM 256
#define MN_ELEMS (1 << 20)        // CDIM * NPIX
#define QKVSTR (320L * NPIX)      // qkv per-batch stride (elems)

// ---- async global->LDS, 16B per lane (dest = wave-uniform base + lane*16) ---
typedef __attribute__((address_space(1))) const unsigned int g_u32;
typedef __attribute__((address_space(3))) unsigned int l_u32;
__device__ __forceinline__ void glds16(const void* g, void* l) {
  __builtin_amdgcn_global_load_lds((g_u32*)g, (l_u32*)l, 16, 0, 0);
}

// ---- 8-element loaders -> bf16x8 (s8v) --------------------------------------
__device__ inline s8v ld8(const bf16* p) { return *(const s8v*)p; }
__device__ inline s8v ld8(const float* p) {
  float4 f0 = *(const float4*)p;
  float4 f1 = *(const float4*)(p + 4);
  s8v r; bf16* e = (bf16*)&r;
  e[0] = __float2bfloat16(f0.x); e[1] = __float2bfloat16(f0.y);
  e[2] = __float2bfloat16(f0.z); e[3] = __float2bfloat16(f0.w);
  e[4] = __float2bfloat16(f1.x); e[5] = __float2bfloat16(f1.y);
  e[6] = __float2bfloat16(f1.z); e[7] = __float2bfloat16(f1.w);
  return r;
}

// ---------------------------------------------------------------------------
// m97-class GEMM, batched split-K: z = batch*nsplit + slice.
// A: [M][K] k-contig bf16 (+ b*abat).  B: [N][K] k-contig bf16 (+ b*bbat).
// Cp partials: fp32 at z*M*N.  Tile 128x128, BK=32, 4 waves (2x2).
// ---------------------------------------------------------------------------
__global__ __launch_bounds__(256) void gemm128(
    const bf16* __restrict__ A, const bf16* __restrict__ Bm,
    float* __restrict__ Cp, int N, int K, int nchunk, int nsplit,
    long abat, long bbat)
{
  __shared__ bf16 a_s[128 * 32];   // [row][k], NO padding (glds layout)
  __shared__ bf16 b_s[128 * 32];
  const int tid = threadIdx.x;
  const int z = blockIdx.z;
  const int bb = z / nsplit, ks = z - bb * nsplit;
  A  += bb * abat;
  Bm += bb * bbat;
  const int w = tid >> 6, lane = tid & 63;
  const int l15 = lane & 15, oct = lane >> 4;
  const int wr = w >> 1, wc = w & 1;
  const int m0 = blockIdx.y * 128, n0 = blockIdx.x * 128;
  const int kc0 = ks * nchunk, kc1 = kc0 + nchunk;

  const int srow = lane >> 2, skoff = (lane & 3) * 8;
  const long aRow0 = (long)(m0 + (w << 4) + srow) * K;
  const long aRow1 = (long)(m0 + ((w + 4) << 4) + srow) * K;
  const long bRow0 = (long)(n0 + (w << 4) + srow) * K;
  const long bRow1 = (long)(n0 + ((w + 4) << 4) + srow) * K;
  bf16* lA0 = a_s + (w) * 512;
  bf16* lA1 = a_s + (w + 4) * 512;
  bf16* lB0 = b_s + (w) * 512;
  bf16* lB1 = b_s + (w + 4) * 512;

  f4v acc[4][4];
  #pragma unroll
  for (int i = 0; i < 4; ++i)
    #pragma unroll
    for (int j = 0; j < 4; ++j) acc[i][j] = (f4v){0.f, 0.f, 0.f, 0.f};

  for (int kc = kc0; kc < kc1; ++kc) {
    const int kb = kc * 32 + skoff;
    glds16(A + aRow0 + kb, lA0);
    glds16(A + aRow1 + kb, lA1);
    glds16(Bm + bRow0 + kb, lB0);
    glds16(Bm + bRow1 + kb, lB1);
    __syncthreads();
    s8v af[4], bfv[4];
    #pragma unroll
    for (int st = 0; st < 4; ++st)
      af[st] = *(const s8v*)(a_s + (wr * 64 + st * 16 + l15) * 32 + oct * 8);
    #pragma unroll
    for (int nt = 0; nt < 4; ++nt)
      bfv[nt] = *(const s8v*)(b_s + (wc * 64 + nt * 16 + l15) * 32 + oct * 8);
    #pragma unroll
    for (int st = 0; st < 4; ++st)
      #pragma unroll
      for (int nt = 0; nt < 4; ++nt)
        acc[st][nt] = __builtin_amdgcn_mfma_f32_16x16x32_bf16(af[st], bfv[nt], acc[st][nt], 0, 0, 0);
    __syncthreads();
  }

  float* Cz = Cp + (long)z * ((long)gridDim.y * 128) * N;
  #pragma unroll
  for (int st = 0; st < 4; ++st) {
    const int gm = m0 + wr * 64 + st * 16 + oct * 4;
    #pragma unroll
    for (int nt = 0; nt < 4; ++nt) {
      const int gn = n0 + wc * 64 + nt * 16 + l15;
      #pragma unroll
      for (int r = 0; r < 4; ++r)
        Cz[(long)(gm + r) * N + gn] = acc[st][nt][r];
    }
  }
}

// ---------------------------------------------------------------------------
// Legacy 64x64 GEMM. TA=1: A[K][M] -> A^T*B.  EXP=1 (S-GEMM): writes exp(s)
// and atomically accumulates row sums into lsum[z*4096 + row].
// ---------------------------------------------------------------------------
template<int TA, int TB, int BIAS, int EXP, typename TAe, typename TBe>
__global__ __launch_bounds__(256) void gemm_k(
    const TAe* __restrict__ A, const TBe* __restrict__ Bm,
    const float* __restrict__ bias, bf16* __restrict__ Cm,
    int M, int N, int K, long abat, long bbat, long cbat, int nchunk,
    float* __restrict__ lsum)
{
  __shared__ bf16 a_s[64][40];
  __shared__ bf16 b_s[64][40];
  const int tid = threadIdx.x;
  A  += blockIdx.z * abat;
  Bm += blockIdx.z * bbat;
  Cm += blockIdx.z * cbat;
  const int m0 = blockIdx.y * 64, n0 = blockIdx.x * 64;
  const int w = tid >> 6, lane = tid & 63;
  const int l15 = lane & 15, oct = lane >> 4;

  f4v acc[4];
  #pragma unroll
  for (int i = 0; i < 4; ++i) acc[i] = (f4v){0.f, 0.f, 0.f, 0.f};

  int a_i0, a_i1, b_i0, b_i1;
  if (TA == 0) { a_i0 = tid >> 2; a_i1 = (tid & 3) * 8; }
  else         { a_i0 = tid >> 3; a_i1 = (tid & 7) * 8; }
  if (TB == 0) { b_i0 = tid >> 3; b_i1 = (tid & 7) * 8; }
  else         { b_i0 = tid >> 2; b_i1 = (tid & 3) * 8; }

  s8v pa, pb;
  auto ldA = [&](int kc, s8v& d) {
    if (TA == 0) {
      if (m0 + a_i0 < M) d = ld8(A + (long)(m0 + a_i0) * K + kc * 32 + a_i1);
      else d = (s8v){0,0,0,0,0,0,0,0};
    } else {
      d = ld8(A + (long)(kc * 32 + a_i0) * M + m0 + a_i1);
    }
  };
  auto ldB = [&](int kc, s8v& d) {
    if (TB == 0) d = ld8(Bm + (long)(kc * 32 + b_i0) * N + n0 + b_i1);
    else         d = ld8(Bm + (long)(n0 + b_i0) * K + kc * 32 + b_i1);
  };

  ldA(0, pa); ldB(0, pb);
  for (int kc = 0; kc < nchunk; ++kc) {
    if (TA == 0) {
      *(s8v*)&a_s[a_i0][a_i1] = pa;
    } else {
      const bf16* e = (const bf16*)&pa;
      #pragma unroll
      for (int j = 0; j < 8; ++j) a_s[a_i1 + j][a_i0] = e[j];
    }
    if (TB == 0) {
      const bf16* e = (const bf16*)&pb;
      #pragma unroll
      for (int j = 0; j < 8; ++j) b_s[b_i1 + j][b_i0] = e[j];
    } else {
      *(s8v*)&b_s[b_i0][b_i1] = pb;
    }
    __syncthreads();
    if (kc + 1 < nchunk) { ldA(kc + 1, pa); ldB(kc + 1, pb); }
    s8v af = *(const s8v*)&a_s[w * 16 + l15][oct * 8];
    #pragma unroll
    for (int nt = 0; nt < 4; ++nt) {
      s8v bfr = *(const s8v*)&b_s[nt * 16 + l15][oct * 8];
      acc[nt] = __builtin_amdgcn_mfma_f32_16x16x32_bf16(af, bfr, acc[nt], 0, 0, 0);
    }
    __syncthreads();
  }
  const int gm_base = m0 + w * 16 + oct * 4;
  if (EXP) {
    // exp + row-sum (softmax denominators); rows always < M here (M=4096)
    float rs[4] = {0.f, 0.f, 0.f, 0.f};
    #pragma unroll
    for (int nt = 0; nt < 4; ++nt) {
      #pragma unroll
      for (int r = 0; r < 4; ++r) {
        float e = __expf(acc[nt][r]);
        rs[r] += e;
        Cm[(long)(gm_base + r) * N + n0 + nt * 16 + l15] = __float2bfloat16(e);
      }
    }
    #pragma unroll
    for (int r = 0; r < 4; ++r) {
      #pragma unroll
      for (int s = 1; s < 16; s <<= 1) rs[r] += __shfl_xor(rs[r], s);
    }
    if (l15 == 0) {
      #pragma unroll
      for (int r = 0; r < 4; ++r)
        atomicAdd(lsum + blockIdx.z * 4096 + gm_base + r, rs[r]);
    }
  } else {
    #pragma unroll
    for (int nt = 0; nt < 4; ++nt) {
      #pragma unroll
      for (int r = 0; r < 4; ++r) {
        int gm = gm_base + r;
        if (gm < M) {
          float vv = acc[nt][r];
          if (BIAS) vv += bias[gm];
          Cm[(long)gm * N + n0 + nt * 16 + l15] = __float2bfloat16(vv);
        }
      }
    }
  }
}

// ---- split-K reducer + bias (conv path) -------------------------------------
__global__ __launch_bounds__(256) void reduce_bias_k(
    const float* __restrict__ part, const float* __restrict__ bias,
    bf16* __restrict__ out, int nsplit)
{
  const int g4 = (blockIdx.x * 256 + threadIdx.x) * 4;
  const int b = g4 >> 20, i = g4 & (MN_ELEMS - 1);
  const float* p0 = part + (long)b * nsplit * MN_ELEMS + i;
  float4 s = *(const float4*)p0;
  for (int p = 1; p < nsplit; ++p) {
    float4 t = *(const float4*)(p0 + (long)p * MN_ELEMS);
    s.x += t.x; s.y += t.y; s.z += t.z; s.w += t.w;
  }
  float bv = bias[i >> 12];
  s.x += bv; s.y += bv; s.z += bv; s.w += bv;
  s4v o; bf16* e = (bf16*)&o;
  e[0] = __float2bfloat16(s.x); e[1] = __float2bfloat16(s.y);
  e[2] = __float2bfloat16(s.z); e[3] = __float2bfloat16(s.w);
  *(s4v*)(out + g4) = o;
}

// ---- split-K reducer + softmax normalize (PV path): /= lsum[b][n] -----------
__global__ __launch_bounds__(256) void reduce_norm_k(
    const float* __restrict__ part, const float* __restrict__ lsum,
    bf16* __restrict__ out, int nsplit)
{
  const int g4 = (blockIdx.x * 256 + threadIdx.x) * 4;
  const int b = g4 >> 20, i = g4 & (MN_ELEMS - 1), n = i & 4095;
  const float* p0 = part + (long)b * nsplit * MN_ELEMS + i;
  float4 s = *(const float4*)p0;
  for (int p = 1; p < nsplit; ++p) {
    float4 t = *(const float4*)(p0 + (long)p * MN_ELEMS);
    s.x += t.x; s.y += t.y; s.z += t.z; s.w += t.w;
  }
  float4 l = *(const float4*)(lsum + b * 4096 + n);
  s.x /= l.x; s.y /= l.y; s.z /= l.z; s.w /= l.w;
  s4v o; bf16* e = (bf16*)&o;
  e[0] = __float2bfloat16(s.x); e[1] = __float2bfloat16(s.y);
  e[2] = __float2bfloat16(s.z); e[3] = __float2bfloat16(s.w);
  *(s4v*)(out + g4) = o;
}

// ---- zero the softmax-denominator array (8192 fp32) -------------------------
__global__ __launch_bounds__(256) void zerol_k(float* __restrict__ l)
{
  l[blockIdx.x * 256 + threadIdx.x] = 0.f;
}

// ---- concat q/k(/v) weights+biases into fp32 [M][256] + [M] -----------------
__global__ __launch_bounds__(256) void cat_k(
    const float* __restrict__ wq, const float* __restrict__ bq,
    const float* __restrict__ wk, const float* __restrict__ bk,
    const float* __restrict__ wv, const float* __restrict__ bv,
    float* __restrict__ wcat, float* __restrict__ bcat, int M)
{
  int idx = blockIdx.x * 256 + threadIdx.x;
  int total = M << 8;
  if (idx < total) {
    int r = idx >> 8, c = idx & 255;
    float v;
    if (r < 32) v = wq[r * 256 + c];
    else if (r < 64) v = wk[(r - 32) * 256 + c];
    else v = wv[(r - 64) * 256 + c];
    wcat[idx] = v;
  } else if (idx < total + M) {
    int r = idx - total;
    bcat[r] = (r < 32) ? bq[r] : (r < 64) ? bk[r - 32] : bv[r - 64];
  }
}

// ---- both convs' weights: fp32 [O][C][9] -> bf16 [O][j*256+c] ---------------
__global__ __launch_bounds__(256) void cvtw2_k(
    const float* __restrict__ w1, const float* __restrict__ w2,
    bf16* __restrict__ o1, bf16* __restrict__ o2)
{
  const float* in = blockIdx.y ? w2 : w1;
  bf16* out = blockIdx.y ? o2 : o1;
  int idx = blockIdx.x * 256 + threadIdx.x;       // 589824 per conv
  int o = idx / 2304, r = idx % 2304;
  int j = r >> 8, c = r & 255;
  out[idx] = __float2bfloat16(in[(o * 256 + c) * 9 + j]);
}

// ---------------------------------------------------------------------------
// LDS-transpose im2col, K-reordered: colT[n][j*256+c], j = dy*3+dx.
// ---------------------------------------------------------------------------
__global__ __launch_bounds__(256) void im2colT2_k(const bf16* __restrict__ x,
                                                  bf16* __restrict__ colT)
{
  __shared__ bf16 lds[3 * 66 * 66];
  const int tid = threadIdx.x;
  const int h = blockIdx.x, c0 = blockIdx.y * 64;
  x    += (long)blockIdx.z * CDIM * NPIX;
  colT += (long)blockIdx.z * 2304L * NPIX;

  if (tid < 192) {
    int row = tid >> 6, c = tid & 63;
    lds[(row * 66 + 0) * 66 + c] = __float2bfloat16(0.f);
    lds[(row * 66 + 65) * 66 + c] = __float2bfloat16(0.f);
  }
  const int w2 = tid & 31, chi = tid >> 5;
  #pragma unroll
  for (int it = 0; it < 24; ++it) {
    int row = it >> 3, cg = it & 7;
    int c = cg * 8 + chi;
    int hh = h + row - 1;
    unsigned int pix = 0;
    if ((unsigned)hh < 64u)
      pix = *(const unsigned int*)(x + (long)(c0 + c) * 4096 + hh * 64 + w2 * 2);
    const bf16* pp = (const bf16*)&pix;
    lds[(row * 66 + (w2 * 2 + 1)) * 66 + c] = pp[0];
    lds[(row * 66 + (w2 * 2 + 2)) * 66 + c] = pp[1];
  }
  __syncthreads();
  const int cg8 = tid & 7, wq = tid >> 3;
  #pragma unroll
  for (int j = 0; j < 9; ++j) {
    const int dy = j / 3, dx = j % 3;
    #pragma unroll
    for (int half = 0; half < 2; ++half) {
      int w = wq + half * 32;
      s8v v = *(const s8v*)&lds[(dy * 66 + (w + dx)) * 66 + cg8 * 8];
      *(s8v*)(colT + (long)(h * 64 + w) * 2304 + j * 256 + c0 + cg8 * 8) = v;
    }
  }
}

// ---- 16-elem row load/store helpers ----------------------------------------
__device__ inline void ld16(const bf16* p, float* v) {
  s8v r0 = *(const s8v*)p, r1 = *(const s8v*)(p + 8);
  const bf16* e0 = (const bf16*)&r0; const bf16* e1 = (const bf16*)&r1;
  #pragma unroll
  for (int j = 0; j < 8; ++j) { v[j] = __bfloat162float(e0[j]); v[8 + j] = __bfloat162float(e1[j]); }
}
__device__ inline void ld16(const float* p, float* v) {
  #pragma unroll
  for (int q = 0; q < 4; ++q) {
    float4 f = *(const float4*)(p + q * 4);
    v[q * 4 + 0] = f.x; v[q * 4 + 1] = f.y; v[q * 4 + 2] = f.z; v[q * 4 + 3] = f.w;
  }
}
__device__ inline void st16(bf16* p, const float* v) {
  s8v o0, o1v; bf16* f0 = (bf16*)&o0; bf16* f1 = (bf16*)&o1v;
  #pragma unroll
  for (int j = 0; j < 8; ++j) { f0[j] = __float2bfloat16(v[j]); f1[j] = __float2bfloat16(v[8 + j]); }
  *(s8v*)p = o0; *(s8v*)(p + 8) = o1v;
}
__device__ inline void st16(float* p, const float* v) {
  #pragma unroll
  for (int q = 0; q < 4; ++q) {
    float4 f; f.x = v[q * 4 + 0]; f.y = v[q * 4 + 1]; f.z = v[q * 4 + 2]; f.w = v[q * 4 + 3];
    *(float4*)(p + q * 4) = f;
  }
}

// ---- fused InstanceNorm: out = inorm(g*a + b) per row of 4096 --------------
template<typename TAe, typename TBe, typename TOe, int G>
__global__ __launch_bounds__(256) void inorm_k(
    const TAe* __restrict__ a, const TBe* __restrict__ b,
    const float* __restrict__ g, TOe* __restrict__ out)
{
  __shared__ float red[8];
  const int tid = threadIdx.x;
  const long base = (long)blockIdx.x * NPIX + tid * 16;
  float gv = G ? *g : 1.f;
  float va[16], vbv[16], v[16];
  ld16(a + base, va);
  ld16(b + base, vbv);
  #pragma unroll
  for (int j = 0; j < 16; ++j) v[j] = gv * va[j] + vbv[j];
  float sum = 0.f, sq = 0.f;
  #pragma unroll
  for (int j = 0; j < 16; ++j) { sum += v[j]; sq += v[j] * v[j]; }
  #pragma unroll
  for (int s = 32; s; s >>= 1) { sum += __shfl_xor(sum, s); sq += __shfl_xor(sq, s); }
  if ((tid & 63) == 0) { red[tid >> 6] = sum; red[4 + (tid >> 6)] = sq; }
  __syncthreads();
  sum = red[0] + red[1] + red[2] + red[3];
  sq  = red[4] + red[5] + red[6] + red[7];
  float mean = sum * (1.f / NPIX);
  float var  = fmaxf(sq * (1.f / NPIX) - mean * mean, 0.f);
  float rstd = rsqrtf(var + 1e-5f);
  float o[16];
  #pragma unroll
  for (int j = 0; j < 16; ++j) o[j] = (v[j] - mean) * rstd;
  st16(out + base, o);
}

// ---- host-side helpers ------------------------------------------------------
static const long CN  = (long)CDIM * NPIX;
static const long SBAT = (long)NPIX * NPIX;

// S-GEMM (+exp +rowsum), PV split-K, normalize. q at qkv, k at +32N, v at +64N.
static void attn_core(bf16* qkv, bf16* Sb, float* lsum, float* part, bf16* t0,
                      hipStream_t stream)
{
  dim3 TB(256);
  zerol_k<<<dim3(32), TB, 0, stream>>>(lsum);
  gemm_k<1,0,0,1,bf16,bf16><<<dim3(64,64,2), TB, 0, stream>>>(
      qkv, qkv + 32 * NPIX, nullptr, Sb, NPIX, NPIX, 32, QKVSTR, QKVSTR, SBAT, 1, lsum);
  gemm128<<<dim3(32,2,8), TB, 0, stream>>>(qkv + 64 * NPIX, Sb, part, NPIX, NPIX, 32, 4, QKVSTR, SBAT);
  reduce_norm_k<<<dim3(2048), TB, 0, stream>>>(part, lsum, t0, 4);
}

static void run_conv(const bf16* src, const bf16* wcvt, const float* cb,
                     bf16* colT, float* part, bf16* dst, hipStream_t stream)
{
  dim3 TB(256);
  im2colT2_k<<<dim3(64, 4, 2), TB, 0, stream>>>(src, colT);
  gemm128<<<dim3(32,2,8), TB, 0, stream>>>(wcvt, colT, part, NPIX, 2304, 18, 4, 0L, 2304L * NPIX);
  reduce_bias_k<<<dim3(2048), TB, 0, stream>>>(part, cb, dst, 4);
}

// ---------------------------------------------------------------------------
extern "C" void kernel_launch(void* const* d_in, const int* in_sizes, int n_in,
                              void* d_out, int out_size, void* d_ws, size_t ws_size,
                              hipStream_t stream)
{
  (void)in_sizes; (void)n_in; (void)out_size; (void)ws_size;
  const float* x = (const float*)d_in[0];
  const float* y = (const float*)d_in[1];
  auto W = [&](int i) { return (const float*)d_in[i]; };

  char* wp = (char*)d_ws;
  auto take = [&](size_t nbytes) { char* p = wp; wp += (nbytes + 255) & ~(size_t)255; return p; };
  bf16*  qkv   = (bf16*)take(2 * (size_t)QKVSTR * 2);    // 5.0 MiB; conv dst aliases
  bf16*  t0    = (bf16*)take(2 * CN * 2);                // attention O
  bf16*  u1    = (bf16*)take(2 * CN * 2);
  bf16*  u2    = (bf16*)take(2 * CN * 2);
  bf16*  u3    = (bf16*)take(2 * CN * 2);
  bf16*  u4    = (bf16*)take(2 * CN * 2);
  bf16*  Sb    = (bf16*)take(2 * (size_t)SBAT * 2);      // 64 MiB; colT aliases
  bf16*  colT  = Sb;
  bf16*  wcvt1 = (bf16*)take((size_t)589824 * 2);
  bf16*  wcvt2 = (bf16*)take((size_t)589824 * 2);
  float* wcat1 = (float*)take((size_t)81920 * 4);
  float* bcat1 = (float*)take(320 * 4);
  float* wcat2 = (float*)take((size_t)81920 * 4);
  float* bcat2 = (float*)take(320 * 4);
  float* wqk   = (float*)take((size_t)16384 * 4);
  float* bqk   = (float*)take(64 * 4);
  float* lsum  = (float*)take(8192 * 4);
  float* part  = (float*)take((size_t)8 * MN_ELEMS * 4); // 32 MiB (2 batches x 4 slices)
  bf16*  cvout = qkv;                                    // conv output (aliased)

  dim3 TB(256);

  // ---- prep: weight concat/convert (activation-independent) ----
  cat_k<<<dim3(322), TB, 0, stream>>>(W(2), W(3), W(4), W(5), W(6), W(7), wcat1, bcat1, 320);
  cat_k<<<dim3(322), TB, 0, stream>>>(W(9), W(10), W(11), W(12), W(13), W(14), wcat2, bcat2, 320);
  cat_k<<<dim3(65),  TB, 0, stream>>>(W(16), W(17), W(18), W(19), nullptr, nullptr, wqk, bqk, 64);
  cvtw2_k<<<dim3(2304, 2), TB, 0, stream>>>(W(23), W(25), wcvt1, wcvt2);

  // ---- stage A: out_1 = inorm(sa1(x)); out_2 = inorm(out_1 + conv1(out_1))
  gemm_k<0,0,1,0,float,float><<<dim3(64,5,2), TB, 0, stream>>>(
      wcat1, x, bcat1, qkv, 320, NPIX, 256, 0L, CN, QKVSTR, 8, nullptr);
  attn_core(qkv, Sb, lsum, part, t0, stream);
  inorm_k<bf16,float,bf16,1><<<dim3(512), TB, 0, stream>>>(t0, x, W(8), u1);
  run_conv(u1, wcvt1, W(24), colT, part, cvout, stream);
  inorm_k<bf16,bf16,bf16,0><<<dim3(512), TB, 0, stream>>>(u1, cvout, nullptr, u2);

  // ---- stage B: out_3 = inorm(sa2(y))
  gemm_k<0,0,1,0,float,float><<<dim3(64,5,2), TB, 0, stream>>>(
      wcat2, y, bcat2, qkv, 320, NPIX, 256, 0L, CN, QKVSTR, 8, nullptr);
  attn_core(qkv, Sb, lsum, part, t0, stream);
  inorm_k<bf16,float,bf16,1><<<dim3(512), TB, 0, stream>>>(t0, y, W(15), u3);

  // ---- stage C: top attention (q,k from out_2; v from out_3), residual = y
  gemm_k<0,0,1,0,float,bf16><<<dim3(64,1,2), TB, 0, stream>>>(
      wqk, u2, bqk, qkv, 64, NPIX, 256, 0L, CN, QKVSTR, 8, nullptr);
  gemm_k<0,0,1,0,float,bf16><<<dim3(64,4,2), TB, 0, stream>>>(
      W(20), u3, W(21), qkv + 64 * NPIX, 256, NPIX, 256, 0L, CN, QKVSTR, 8, nullptr);
  attn_core(qkv, Sb, lsum, part, t0, stream);
  inorm_k<bf16,float,bf16,1><<<dim3(512), TB, 0, stream>>>(t0, y, W(22), u1);   // o1
  inorm_k<bf16,bf16,bf16,0><<<dim3(512), TB, 0, stream>>>(u1, u3, nullptr, u4); // o2
  run_conv(u4, wcvt2, W(26), colT, part, cvout, stream);
  inorm_k<bf16,bf16,float,0><<<dim3(512), TB, 0, stream>>>(u4, cvout, nullptr, (float*)d_out);
}